// Round 39
// baseline (399.359 us; speedup 1.0000x reference)
//
#include <hip/hip_runtime.h>
#include <hip/hip_fp16.h>

#define N_NODES 25000
#define M_PAD   25024            // multiple of 16 (1564 tiles)
#define N_TILES 1564
#define N_EDGES 300000
#define IN_DIM  32
#define EDFD    16
#define HIDD    256
#define HEADS   4
#define NACT    16
#define NGRAPH  64
#define KWIRE   1024
#define POOL_NB 64
#define LOG2E   1.44269504088896f

typedef _Float16 half8v __attribute__((ext_vector_type(8)));
typedef __attribute__((ext_vector_type(4))) float f32x4;

// ---------------------------------------------------------------- helpers
__device__ __forceinline__ float leaky(float v) { return v > 0.f ? v : 0.2f * v; }

// ---------------------------------------------------------------- CSR build (both directions)
__global__ __launch_bounds__(256) void k_deg2(const int* __restrict__ ei,
                                              int* __restrict__ deg,
                                              int* __restrict__ deg2) {
    int e = blockIdx.x * 256 + threadIdx.x;
    if (e >= N_EDGES) return;
    atomicAdd(&deg[ei[N_EDGES + e]], 1);
    atomicAdd(&deg2[ei[e]], 1);
}

// parallel exclusive scan: 1024 threads, 25 elems/thread, Hillis-Steele tree in LDS
__global__ __launch_bounds__(1024) void k_scan2(const int* __restrict__ degA, int* __restrict__ rpA,
                                                const int* __restrict__ degB, int* __restrict__ rpB) {
    const int* deg = blockIdx.x ? degB : degA;
    int* rowptr    = blockIdx.x ? rpB : rpA;
    __shared__ int part[1024];
    int t = threadIdx.x;
    const int CH = 25;                         // 1024*25 = 25600 >= 25001
    int base = t * CH;
    int s = 0;
    for (int i = 0; i < CH; ++i) {
        int idx = base + i;
        if (idx < N_NODES) s += deg[idx];
    }
    part[t] = s;
    __syncthreads();
    #pragma unroll
    for (int off = 1; off < 1024; off <<= 1) { // inclusive scan, log steps
        int v = (t >= off) ? part[t - off] : 0;
        __syncthreads();
        part[t] += v;
        __syncthreads();
    }
    int run = (t == 0) ? 0 : part[t - 1];      // exclusive prefix for this chunk
    for (int i = 0; i < CH; ++i) {
        int idx = base + i;
        if (idx < N_NODES) { rowptr[idx] = run; run += deg[idx]; }
    }
    if (N_NODES >= base && N_NODES < base + CH) rowptr[N_NODES] = run;
}

// scatter + permute edge_attr into src-CSR order (fp16) + dst-CSR position map
__global__ __launch_bounds__(256) void k_scatter2(const int* __restrict__ ei,
                                                  const float* __restrict__ ea,
                                                  const int* __restrict__ rowptr,
                                                  const int* __restrict__ rowptr2,
                                                  int* __restrict__ cursor,
                                                  int* __restrict__ cursor2,
                                                  int* __restrict__ csrc,
                                                  int* __restrict__ cdst,
                                                  int* __restrict__ posMap,
                                                  __half* __restrict__ eaP) {
    int e = blockIdx.x * 256 + threadIdx.x;
    if (e >= N_EDGES) return;
    int src = ei[e], dst = ei[N_EDGES + e];
    int p1 = atomicAdd(&cursor[dst], 1);
    int r1 = rowptr[dst] + p1;
    csrc[r1] = src;
    int p2 = atomicAdd(&cursor2[src], 1);
    int r2 = rowptr2[src] + p2;
    cdst[r2] = dst;
    posMap[r2] = r1;                             // where this edge's msg lands (dst-CSR)
    const float4* src4 = (const float4*)(ea + (size_t)e * EDFD);
    __half2* dp = (__half2*)(eaP + (size_t)r2 * EDFD);
    #pragma unroll
    for (int q = 0; q < EDFD / 4; ++q) {
        float4 v = src4[q];
        dp[q * 2]     = __float22half2_rn(make_float2(v.x, v.y));
        dp[q * 2 + 1] = __float22half2_rn(make_float2(v.z, v.w));
    }
}

// ---------------------------------------------------------------- merged weight prep
// block ranges: [0,128) w2perm | [128,256) wb1 | [256,1280) wb2 | [1280,4405) xcvt
//               4405 wa1 | [4406,4410) wa2 | [4410,4412) w1t
// wa*/wd* prescaled by LOG2E so agg kernels can use exp2 (leaky is pos-homogeneous).
__global__ __launch_bounds__(256) void k_prep(const float* __restrict__ w2,
                                              const float* __restrict__ W1,
                                              const float* __restrict__ W2,
                                              const float* __restrict__ a1s,
                                              const float* __restrict__ a1d,
                                              const float* __restrict__ a2s,
                                              const float* __restrict__ a2d,
                                              const float* __restrict__ x,
                                              const float* __restrict__ b2,
                                              const float* __restrict__ w1,
                                              __half* __restrict__ wtt,
                                              __half* __restrict__ wb1,
                                              __half* __restrict__ wb2,
                                              float* __restrict__ wa1,
                                              float* __restrict__ wd1,
                                              float* __restrict__ wa2,
                                              float* __restrict__ wd2,
                                              __half* __restrict__ xf,
                                              float* __restrict__ xb,
                                              __half* __restrict__ w1t) {
    int bid = blockIdx.x, t = threadIdx.x;
    if (bid < 128) {                             // enc_w2 perm: wtt[co][i]
        int idx = bid * 256 + t;                 // co*32+i
        int co = idx >> 5, i = idx & 31;
        wtt[idx] = __float2half(w2[(co >> 5) * 1024 + i * 32 + (co & 31)]);
    } else if (bid < 256) {                      // wb1[d][k], k=h*32+i
        int idx = (bid - 128) * 256 + t;
        int d = idx >> 7, k = idx & 127;
        int h = k >> 5, i = k & 31;
        wb1[idx] = __float2half(0.25f * W1[i * 1024 + h * 256 + d]);
    } else if (bid < 1280) {                     // wb2[d][k], k=h*256+i
        int idx = (bid - 256) * 256 + t;
        int d = idx >> 10, k = idx & 1023;
        int h = k >> 8, i = k & 255;
        wb2[idx] = __float2half(0.25f * W2[i * 1024 + h * 256 + d]);
    } else if (bid < 4405) {                     // xcvt
        int idx = (bid - 1280) * 256 + t;
        if (idx >= N_NODES * 32) return;
        int n = idx >> 5, o = idx & 31;
        xf[idx] = __float2half(x[idx]);
        float s = 0.f;
        for (int i = 0; i < 32; ++i) s += x[n * 32 + i] * b2[i * 32 + o];
        xb[idx] = s;
    } else if (bid == 4405) {                    // wa1/wd1 (128 lanes), log2e-prescaled
        if (t >= 128) return;
        int h = t >> 5, i = t & 31;
        float s = 0.f, sd = 0.f;
        for (int d = 0; d < 256; ++d) {
            float w = W1[i * 1024 + h * 256 + d];
            s  += w * a1s[h * 256 + d];
            sd += w * a1d[h * 256 + d];
        }
        wa1[t] = s * LOG2E; wd1[t] = sd * LOG2E;
    } else if (bid < 4410) {                     // wa2/wd2, log2e-prescaled
        int idx = (bid - 4406) * 256 + t;        // h*256+i
        if (idx >= 1024) return;
        int h = idx >> 8, i = idx & 255;
        float s = 0.f, sd = 0.f;
        for (int d = 0; d < 256; ++d) {
            float w = W2[i * 1024 + h * 256 + d];
            s  += w * a2s[h * 256 + d];
            sd += w * a2d[h * 256 + d];
        }
        wa2[idx] = s * LOG2E; wd2[idx] = sd * LOG2E;
    } else {                                     // w1t[j][k] = fp16(w1[k*32+j])
        int idx = (bid - 4410) * 256 + t;        // j*16+k
        if (idx >= 32 * EDFD) return;
        int j = idx >> 4, k = idx & 15;
        w1t[idx] = __float2half(w1[k * 32 + j]);
    }
}

// ---------------------------------------------------------------- NNConv via MFMA
// wave per src: msgE[16 edges,32] = relu(eaP[16,16] @ w1 + b1) @ T[src] + xb[src]
__global__ __launch_bounds__(256) void k_msg3(const int* __restrict__ rowptr2,
                                              const int* __restrict__ posMap,
                                              const __half* __restrict__ eaP,
                                              const __half* __restrict__ w1t,
                                              const float* __restrict__ b1,
                                              const __half* __restrict__ T,
                                              const float* __restrict__ xb,
                                              __half* __restrict__ msgE) {
    int wv = threadIdx.x >> 6, lane = threadIdx.x & 63;
    int src = blockIdx.x * 4 + wv;
    if (src >= N_NODES) return;
    int r0 = rowptr2[src], r1 = rowptr2[src + 1];
    if (r0 == r1) return;
    int lr = lane & 15, lk = (lane >> 4) * 8;

    // B fragments from T[src] (layout [j*32+o]): col lr (B0) and 16+lr (B1), k = lk..lk+7
    half8v bf0, bf1;
    const __half* Tp = T + (size_t)src * 1024;
    #pragma unroll
    for (int q = 0; q < 8; ++q) {
        bf0[q] = (_Float16)__half2float(Tp[(lk + q) * 32 + lr]);
        bf1[q] = (_Float16)__half2float(Tp[(lk + q) * 32 + 16 + lr]);
    }

    // w1 rows lk..lk+7 (fp16, 16 k each) held in registers
    __half2 w1r[8][EDFD / 2];
    #pragma unroll
    for (int q = 0; q < 8; ++q) {
        const __half2* wp = (const __half2*)(w1t + (lk + q) * EDFD);
        #pragma unroll
        for (int k2 = 0; k2 < EDFD / 2; ++k2) w1r[q][k2] = wp[k2];
    }
    float b1r[8];
    #pragma unroll
    for (int q = 0; q < 8; ++q) b1r[q] = b1[lk + q];

    float xb0 = xb[src * 32 + lr], xb1 = xb[src * 32 + 16 + lr];
    int rbase = (lane >> 4) * 4;

    for (int t0 = r0; t0 < r1; t0 += 16) {
        int e = t0 + lr;
        bool ok = (e < r1);
        // MLP for edge e, outputs j = lk..lk+7
        half8v afr;
        if (ok) {
            const __half2* ep = (const __half2*)(eaP + (size_t)e * EDFD);
            __half2 ea2[EDFD / 2];
            #pragma unroll
            for (int k2 = 0; k2 < EDFD / 2; ++k2) ea2[k2] = ep[k2];
            #pragma unroll
            for (int q = 0; q < 8; ++q) {
                float s = b1r[q];
                #pragma unroll
                for (int k2 = 0; k2 < EDFD / 2; ++k2) {
                    float2 v = __half22float2(ea2[k2]);
                    float2 w = __half22float2(w1r[q][k2]);
                    s += v.x * w.x + v.y * w.y;
                }
                afr[q] = (_Float16)fmaxf(s, 0.f);
            }
        } else {
            #pragma unroll
            for (int q = 0; q < 8; ++q) afr[q] = (_Float16)0.f;
        }
        f32x4 c0 = {0.f, 0.f, 0.f, 0.f}, c1 = {0.f, 0.f, 0.f, 0.f};
        c0 = __builtin_amdgcn_mfma_f32_16x16x32_f16(afr, bf0, c0, 0, 0, 0);
        c1 = __builtin_amdgcn_mfma_f32_16x16x32_f16(afr, bf1, c1, 0, 0, 0);
        #pragma unroll
        for (int r = 0; r < 4; ++r) {
            int er = t0 + rbase + r;
            if (er < r1) {
                int pm = posMap[er];
                msgE[(size_t)pm * 32 + lr]      = __float2half(c0[r] + xb0);
                msgE[(size_t)pm * 32 + 16 + lr] = __float2half(c1[r] + xb1);
            }
        }
    }
}

// h0 = relu(sum(msgE)/deg + x@root_w + bias) -> fp16, fused layer1 es/ed (log2-space)
__global__ __launch_bounds__(256) void k_h0e(const float* __restrict__ x,
                                             const float* __restrict__ root_w,
                                             const float* __restrict__ nn_bias,
                                             const __half* __restrict__ msgE,
                                             const int* __restrict__ rowptr,
                                             const float* __restrict__ wa,
                                             const float* __restrict__ wd,
                                             __half* __restrict__ h0f,
                                             float* __restrict__ es,
                                             float* __restrict__ ed) {
    int t = threadIdx.x;
    int ng = t >> 5, o = t & 31;
    int n = blockIdx.x * 8 + ng;
    if (n >= N_NODES) return;
    float s = nn_bias[o];
    for (int k = 0; k < IN_DIM; ++k) s += x[n * IN_DIM + k] * root_w[k * 32 + o];
    int r0 = rowptr[n], r1 = rowptr[n + 1];
    float aggv = 0.f;
    for (int r = r0; r < r1; ++r)
        aggv += __half2float(msgE[(size_t)r * 32 + o]);  // sequential 64B reads per group
    float c = fmaxf((float)(r1 - r0), 1.f);
    s += aggv / c;
    float v = fmaxf(s, 0.f);
    h0f[n * IN_DIM + o] = __float2half(v);
    #pragma unroll
    for (int h = 0; h < 4; ++h) {
        float ss = v * wa[h * 32 + o];
        float dd = v * wd[h * 32 + o];
        #pragma unroll
        for (int off = 16; off; off >>= 1) {
            ss += __shfl_down(ss, off, 32);
            dd += __shfl_down(dd, off, 32);
        }
        if (o == 0) { es[n * 4 + h] = ss; ed[n * 4 + h] = dd; }
    }
}

// ---------------------------------------------------------------- GEMM 1: T = xf @ wtt^T, out [M,1024] fp16
__global__ __launch_bounds__(256, 2) void k_gemT(const __half* __restrict__ A,
                                                 const __half* __restrict__ Wt,
                                                 __half* __restrict__ C) {
    __shared__ __half cst[4][16 * 36];
    int t = threadIdx.x, wid = t >> 6, lane = t & 63;
    int lr = lane & 15, lk = (lane >> 4) * 8;

    int bid = blockIdx.x;
    int xcd = bid & 7, j = bid >> 3;
    int sx = j & 31;
    int y = ((j >> 5) << 3) | xcd;            // 0..103
    int n0 = sx * 32;

    half8v bfr[2];
    #pragma unroll
    for (int c = 0; c < 2; ++c)
        bfr[c] = *(const half8v*)(Wt + (size_t)(n0 + c * 16 + lr) * 32 + lk);

    int tb = (y * 4 + wid) * 4;
    for (int pp = 0; pp < 4; pp += 2) {
        int tA = tb + pp;
        if (tA >= N_TILES) break;
        int mA = tA * 16, mB = mA + 16;
        half8v aA = *(const half8v*)(A + (size_t)(mA + lr) * 32 + lk);
        half8v aB = *(const half8v*)(A + (size_t)(mB + lr) * 32 + lk);
        f32x4 acc[2][2];
        #pragma unroll
        for (int i = 0; i < 2; ++i)
            #pragma unroll
            for (int c = 0; c < 2; ++c)
                acc[i][c] = (f32x4){0.f, 0.f, 0.f, 0.f};
        acc[0][0] = __builtin_amdgcn_mfma_f32_16x16x32_f16(aA, bfr[0], acc[0][0], 0, 0, 0);
        acc[0][1] = __builtin_amdgcn_mfma_f32_16x16x32_f16(aA, bfr[1], acc[0][1], 0, 0, 0);
        acc[1][0] = __builtin_amdgcn_mfma_f32_16x16x32_f16(aB, bfr[0], acc[1][0], 0, 0, 0);
        acc[1][1] = __builtin_amdgcn_mfma_f32_16x16x32_f16(aB, bfr[1], acc[1][1], 0, 0, 0);

        int rbase = (lane >> 4) * 4;
        #pragma unroll
        for (int ti = 0; ti < 2; ++ti) {
            #pragma unroll
            for (int c = 0; c < 2; ++c)
                #pragma unroll
                for (int r = 0; r < 4; ++r)
                    cst[wid][(rbase + r) * 36 + c * 16 + lr] = __float2half(acc[ti][c][r]);
            int m0 = ti ? mB : mA;
            #pragma unroll
            for (int p = 0; p < 2; ++p) {
                int row = p * 8 + (lane >> 3), hb = lane & 7;
                float2 v = *(const float2*)((const char*)&cst[wid][0] + row * 72 + hb * 8);
                *(float2*)((char*)C + ((size_t)(m0 + row) * 1024 + n0) * 2 + hb * 8) = v;
            }
        }
    }
}

// ---------------------------------------------------------------- GEMM 2: head-mean-folded, out [M,256]
// block = 8 row-tiles x 64 cols; wave owns 2 tiles; A-loads hoisted; A re-read 4x.
// Staging via global_load_lds (linear LDS dest, pre-swizzled global src; same byte placement).
// FUSE_ED: accumulate layer-2 attention scalars es/ed from epilogue values (atomic partials).
template <int K, typename OT, bool FUSE_ED>
__global__ __launch_bounds__(256, 3) void k_gemmo(const __half* __restrict__ A,
                                                  const __half* __restrict__ Wt,
                                                  const float* __restrict__ bias,
                                                  OT* __restrict__ C,
                                                  const float* __restrict__ wa,
                                                  const float* __restrict__ wd,
                                                  float* __restrict__ es,
                                                  float* __restrict__ ed) {
    constexpr int CK  = 128;                    // LDS chunk K-extent
    constexpr int KC  = K / CK;
    constexpr int KSC = CK / 32;
    constexpr int CB  = CK * 2;                 // bytes per LDS col (256)
    __shared__ __half bs[2][64 * CK];           // 64 cols x CK (16KB per buffer)
    __shared__ float cst[4][16 * 36];
    int t = threadIdx.x, wid = t >> 6, lane = t & 63;
    int lr = lane & 15, lk = (lane >> 4) * 8;

    int bid = blockIdx.x;
    int xcd = bid & 7, rest = bid >> 3;
    int strip = rest & 3, yhi = rest >> 2;
    int y = yhi * 8 + xcd;                      // row-group (8 tiles); same y -> same XCD
    if (y >= 196) return;                       // block-uniform early exit (196*8=1568>=1564)
    int n0 = strip * 64;
    float bv[4];
    #pragma unroll
    for (int c = 0; c < 4; ++c) bv[c] = bias[n0 + c * 16 + lr];
    int tb = y * 8 + wid * 2;                   // wave's first tile
    int tA0 = tb     < N_TILES ? tb     : N_TILES - 1;   // clamped (no barrier divergence)
    int tA1 = tb + 1 < N_TILES ? tb + 1 : N_TILES - 1;
    const int swz = (lr & 7) << 4;

    f32x4 acc[2][4];                            // [tile][colblock]
    #pragma unroll
    for (int i = 0; i < 2; ++i)
        #pragma unroll
        for (int c = 0; c < 4; ++c)
            acc[i][c] = (f32x4){0.f, 0.f, 0.f, 0.f};

    // async stage: LDS[lo] = Wt[g(lo ^ swz(col))] -- identical placement to reg-staged XOR write
    #define STAGE_CHUNK(BUF, KCN)                                                              \
        _Pragma("unroll")                                                                      \
        for (int it = 0; it < (64 * CB) / (256 * 16); ++it) {                                  \
            int lo = it * 4096 + wid * 1024 + lane * 16;                                       \
            int col = lo >> 8;                                                                 \
            int go = lo ^ ((col & 7) << 4);                                                    \
            const char* sp_ = (const char*)Wt + ((size_t)(n0 + col) * K + (KCN) * CK) * 2      \
                              + (go & (CB - 1));                                               \
            __builtin_amdgcn_global_load_lds(                                                  \
                (const __attribute__((address_space(1))) void*)sp_,                            \
                (__attribute__((address_space(3))) void*)((char*)bs[BUF] + it * 4096 + wid * 1024), \
                16, 0, 0);                                                                     \
        }

    STAGE_CHUNK(0, 0)
    __syncthreads();

    const __half* pA0 = A + (size_t)(tA0 * 16 + lr) * K + lk;
    const __half* pA1 = A + (size_t)(tA1 * 16 + lr) * K + lk;

    for (int kc = 0; kc < KC; ++kc) {
        int cur = kc & 1;
        if (kc + 1 < KC) {
            STAGE_CHUNK(cur ^ 1, kc + 1)
        }
        // hoist all A fragments for this chunk (8 outstanding 16B loads)
        half8v aH0[KSC], aH1[KSC];
        #pragma unroll
        for (int ks = 0; ks < KSC; ++ks) {
            aH0[ks] = *(const half8v*)(pA0 + kc * CK + ks * 32);
            aH1[ks] = *(const half8v*)(pA1 + kc * CK + ks * 32);
        }
        #pragma unroll
        for (int ks = 0; ks < KSC; ++ks) {
            #pragma unroll
            for (int c = 0; c < 4; ++c) {
                half8v b = *(const half8v*)((const char*)bs[cur] +
                            (((c * 16 + lr) * CB + lk * 2 + ks * 64) ^ swz));
                acc[0][c] = __builtin_amdgcn_mfma_f32_16x16x32_f16(aH0[ks], b, acc[0][c], 0, 0, 0);
                acc[1][c] = __builtin_amdgcn_mfma_f32_16x16x32_f16(aH1[ks], b, acc[1][c], 0, 0, 0);
            }
        }
        if (kc + 1 < KC) __syncthreads();
    }
    #undef STAGE_CHUNK

    int rbase = (lane >> 4) * 4;
    #pragma unroll
    for (int ti = 0; ti < 2; ++ti) {
        if (tb + ti >= N_TILES) break;
        int m0 = (tb + ti) * 16;
        int row = lane >> 2, cg = lane & 3;     // 16 rows x 4 col-groups of 8
        #pragma unroll
        for (int half = 0; half < 2; ++half) {
            #pragma unroll
            for (int c = 0; c < 2; ++c)
                #pragma unroll
                for (int r = 0; r < 4; ++r)
                    cst[wid][(rbase + r) * 36 + c * 16 + lr] =
                        fmaxf(acc[ti][half * 2 + c][r] + bv[half * 2 + c], 0.f);
            int colb = n0 + half * 32;
            const float* sp = &cst[wid][row * 36 + cg * 8];
            if constexpr (sizeof(OT) == 2) {
                __half2 o0 = __float22half2_rn(make_float2(sp[0], sp[1]));
                __half2 o1 = __float22half2_rn(make_float2(sp[2], sp[3]));
                __half2 o2 = __float22half2_rn(make_float2(sp[4], sp[5]));
                __half2 o3 = __float22half2_rn(make_float2(sp[6], sp[7]));
                float4 v = make_float4(__uint_as_float(*(unsigned*)&o0), __uint_as_float(*(unsigned*)&o1),
                                       __uint_as_float(*(unsigned*)&o2), __uint_as_float(*(unsigned*)&o3));
                *(float4*)((__half*)C + (size_t)(m0 + row) * 256 + colb + cg * 8) = v;
            } else {
                float4 v0 = make_float4(sp[0], sp[1], sp[2], sp[3]);
                float4 v1 = make_float4(sp[4], sp[5], sp[6], sp[7]);
                float* cp = (float*)C + (size_t)(m0 + row) * 256 + colb + cg * 8;
                *(float4*)cp = v0;
                *(float4*)(cp + 4) = v1;
            }
            if constexpr (FUSE_ED) {
                int rowg = m0 + row;
                #pragma unroll
                for (int h = 0; h < 4; ++h) {
                    float pes = 0.f, ped = 0.f;
                    #pragma unroll
                    for (int d = 0; d < 8; ++d) {
                        float vv = sp[d];
                        pes += vv * wa[h * 256 + colb + cg * 8 + d];
                        ped += vv * wd[h * 256 + colb + cg * 8 + d];
                    }
                    // reduce across the 4 cg lanes (consecutive lanes 4*row..4*row+3)
                    pes += __shfl_down(pes, 1, 4); pes += __shfl_down(pes, 2, 4);
                    ped += __shfl_down(ped, 1, 4); ped += __shfl_down(ped, 2, 4);
                    if (cg == 0 && rowg < N_NODES) {
                        atomicAdd(&es[rowg * 4 + h], pes);
                        atomicAdd(&ed[rowg * 4 + h], ped);
                    }
                }
            }
        }
    }
}

// ---------------------------------------------------------------- aggregation (softmax fused; log2-space scores)
__global__ __launch_bounds__(256) void k_agg1(const int* __restrict__ rowptr,
                                              const int* __restrict__ csrc,
                                              const float* __restrict__ es,
                                              const float* __restrict__ ed,
                                              const __half* __restrict__ h0f,
                                              __half* __restrict__ agg0) {
    int dst = blockIdx.x * 4 + (threadIdx.x >> 6);
    if (dst >= N_NODES) return;
    int lane = threadIdx.x & 63;
    int h = lane >> 4, i2 = lane & 15;
    float edv = ed[dst * 4 + h];
    float vself = leaky(es[dst * 4 + h] + edv);   // shift = self-loop score (w_self = 1)
    float dn = 1.f;
    int r0 = rowptr[dst], r1 = rowptr[dst + 1];

    __half2 hv = *(const __half2*)(h0f + (size_t)dst * 32 + i2 * 2);
    float2 f = __half22float2(hv);
    float ax = f.x, ay = f.y;
    for (int r = r0; r < r1; ++r) {
        int src = csrc[r];
        float w = exp2f(leaky(es[src * 4 + h] + edv) - vself);
        dn += w;
        __half2 sv = *(const __half2*)(h0f + (size_t)src * 32 + i2 * 2);
        float2 g = __half22float2(sv);
        ax += w * g.x; ay += w * g.y;
    }
    float inv = 1.f / (dn + 1e-16f);
    *(__half2*)(agg0 + (size_t)dst * 128 + h * 32 + i2 * 2) =
        __float22half2_rn(make_float2(ax * inv, ay * inv));
}

__global__ __launch_bounds__(256) void k_agg2(const int* __restrict__ rowptr,
                                              const int* __restrict__ csrc,
                                              const float* __restrict__ es,
                                              const float* __restrict__ ed,
                                              const __half* __restrict__ h1f,
                                              __half* __restrict__ agg1) {
    int dst = blockIdx.x * 4 + (threadIdx.x >> 6);
    if (dst >= N_NODES) return;
    int lane = threadIdx.x & 63;
    float vs[4], edv[4], dn[4];
    float acc[4][4];
    {
        float2 q = *(const float2*)(h1f + (size_t)dst * 256 + lane * 4);
        const __half2* hq = (const __half2*)&q;
        float2 f0 = __half22float2(hq[0]), f1 = __half22float2(hq[1]);
        #pragma unroll
        for (int h = 0; h < 4; ++h) {
            edv[h] = ed[dst * 4 + h];
            vs[h] = leaky(es[dst * 4 + h] + edv[h]);
            dn[h] = 1.f;                          // w_self = 1 under self-loop shift
            acc[h][0] = f0.x; acc[h][1] = f0.y;
            acc[h][2] = f1.x; acc[h][3] = f1.y;
        }
    }
    int r0 = rowptr[dst], r1 = rowptr[dst + 1];
    for (int r = r0; r < r1; ++r) {
        int src = csrc[r];
        float4 esv = *(const float4*)(es + (size_t)src * 4);
        float w0 = exp2f(leaky(esv.x + edv[0]) - vs[0]);
        float w1 = exp2f(leaky(esv.y + edv[1]) - vs[1]);
        float w2 = exp2f(leaky(esv.z + edv[2]) - vs[2]);
        float w3 = exp2f(leaky(esv.w + edv[3]) - vs[3]);
        dn[0] += w0; dn[1] += w1; dn[2] += w2; dn[3] += w3;
        float2 q = *(const float2*)(h1f + (size_t)src * 256 + lane * 4);
        const __half2* hq = (const __half2*)&q;
        float2 f0 = __half22float2(hq[0]), f1 = __half22float2(hq[1]);
        acc[0][0] += w0 * f0.x; acc[0][1] += w0 * f0.y; acc[0][2] += w0 * f1.x; acc[0][3] += w0 * f1.y;
        acc[1][0] += w1 * f0.x; acc[1][1] += w1 * f0.y; acc[1][2] += w1 * f1.x; acc[1][3] += w1 * f1.y;
        acc[2][0] += w2 * f0.x; acc[2][1] += w2 * f0.y; acc[2][2] += w2 * f1.x; acc[2][3] += w2 * f1.y;
        acc[3][0] += w3 * f0.x; acc[3][1] += w3 * f0.y; acc[3][2] += w3 * f1.x; acc[3][3] += w3 * f1.y;
    }
    #pragma unroll
    for (int h = 0; h < 4; ++h) {
        float inv = 1.f / (dn[h] + 1e-16f);
        __half2 o0 = __float22half2_rn(make_float2(acc[h][0] * inv, acc[h][1] * inv));
        __half2 o1 = __float22half2_rn(make_float2(acc[h][2] * inv, acc[h][3] * inv));
        __half2* op = (__half2*)(agg1 + (size_t)dst * 1024 + h * 256 + lane * 4);
        op[0] = o0; op[1] = o1;
    }
}

// ---------------------------------------------------------------- heads (wire + pool merged)
__global__ __launch_bounds__(256) void k_wirepool(const int* __restrict__ wm,
                                                  const float* __restrict__ h2,
                                                  const float* __restrict__ ww,
                                                  const float* __restrict__ wb,
                                                  const int* __restrict__ batch,
                                                  float* __restrict__ out,
                                                  float* __restrict__ pooled,
                                                  float* __restrict__ gcnt) {
    int bid = blockIdx.x;
    if (bid < KWIRE / 4) {                       // wire head
        int k = bid * 4 + (threadIdx.x >> 6);
        int lane = threadIdx.x & 63;
        int n = wm[k];
        float s = 0.f;
        for (int d = lane; d < 256; d += 64) s += h2[(size_t)n * 256 + d] * ww[d];
        #pragma unroll
        for (int off = 32; off; off >>= 1) s += __shfl_down(s, off);
        if (lane == 0) out[k] = s + wb[0];
        return;
    }
    // segmented pooling
    int n0 = (bid - KWIRE / 4) * POOL_NB;
    int n1 = n0 + POOL_NB; if (n1 > N_NODES) n1 = N_NODES;
    int d = threadIdx.x;
    int cur = batch[n0];
    float acc = 0.f, cnt = 0.f;
    for (int n = n0; n < n1; ++n) {
        int g = batch[n];
        if (g != cur) {
            atomicAdd(&pooled[cur * 256 + d], acc);
            if (d == 0) atomicAdd(&gcnt[cur], cnt);
            acc = 0.f; cnt = 0.f; cur = g;
        }
        acc += h2[(size_t)n * 256 + d];
        cnt += 1.f;
    }
    atomicAdd(&pooled[cur * 256 + d], acc);
    if (d == 0) atomicAdd(&gcnt[cur], cnt);
}

__global__ __launch_bounds__(256) void k_act(const float* __restrict__ pooled,
                                             const float* __restrict__ gcnt,
                                             const float* __restrict__ aw,
                                             const float* __restrict__ ab,
                                             float* __restrict__ out) {
    int u = blockIdx.x * 4 + (threadIdx.x >> 6);
    int lane = threadIdx.x & 63;
    if (u >= NGRAPH * NACT) return;
    int g = u >> 4, a = u & 15;
    float c = fmaxf(gcnt[g], 1.f);
    float s = 0.f;
    for (int d = lane; d < 256; d += 64) s += pooled[g * 256 + d] * aw[d * 16 + a];
    #pragma unroll
    for (int off = 32; off; off >>= 1) s += __shfl_down(s, off);
    if (lane == 0) out[KWIRE + u] = s / c + ab[a];
}

// ---------------------------------------------------------------- launch
extern "C" void kernel_launch(void* const* d_in, const int* in_sizes, int n_in,
                              void* d_out, int out_size, void* d_ws, size_t ws_size,
                              hipStream_t stream) {
    const float* x        = (const float*)d_in[0];
    const float* edge_attr= (const float*)d_in[1];
    const int*   wire_mask= (const int*)d_in[2];
    const int*   edge_idx = (const int*)d_in[3];
    const int*   batch    = (const int*)d_in[4];
    const float* enc_w1   = (const float*)d_in[5];
    const float* enc_b1   = (const float*)d_in[6];
    const float* enc_w2   = (const float*)d_in[7];
    const float* enc_b2   = (const float*)d_in[8];
    const float* root_w   = (const float*)d_in[9];
    const float* nn_bias  = (const float*)d_in[10];
    const float* gat1_w   = (const float*)d_in[11];
    const float* gat1_asrc= (const float*)d_in[12];
    const float* gat1_adst= (const float*)d_in[13];
    const float* gat1_b   = (const float*)d_in[14];
    const float* gat2_w   = (const float*)d_in[15];
    const float* gat2_asrc= (const float*)d_in[16];
    const float* gat2_adst= (const float*)d_in[17];
    const float* gat2_b   = (const float*)d_in[18];
    const float* wire_w   = (const float*)d_in[19];
    const float* wire_b   = (const float*)d_in[20];
    const float* act_w    = (const float*)d_in[21];
    const float* act_b    = (const float*)d_in[22];
    float* out = (float*)d_out;

    float* ws = (float*)d_ws;
    size_t off = 0;
    __half* T16   = (__half*)(ws + off); off += (size_t)M_PAD * 1024 / 2;
    __half* agg1f = (__half*)(ws + off); off += (size_t)M_PAD * 1024 / 2;
    __half* agg0f = (__half*)(ws + off); off += (size_t)M_PAD * 128 / 2;
    __half* h0f   = (__half*)(ws + off); off += (size_t)M_PAD * 32 / 2;
    __half* h1f   = (__half*)(ws + off); off += (size_t)M_PAD * 256 / 2;
    __half* xf    = (__half*)(ws + off); off += (size_t)M_PAD * 32 / 2;
    __half* eaP   = (__half*)(ws + off); off += (size_t)N_EDGES * EDFD / 2;
    __half* msgE  = (__half*)(ws + off); off += (size_t)N_EDGES * 32 / 2;
    float* xb     = ws + off; off += 800000;
    float* esb    = ws + off; off += 100000;
    float* edb    = ws + off; off += 100000;
    float* h2     = ws + off; off += (size_t)M_PAD * 256;
    float* pooled = ws + off; off += NGRAPH * 256;
    float* gcnt   = ws + off; off += NGRAPH;
    int* deg      = (int*)(ws + off); off += 25600;   // zero-region start
    int* deg2     = (int*)(ws + off); off += 25600;
    int* cursor   = (int*)(ws + off); off += 25600;
    int* cursor2  = (int*)(ws + off); off += 25600;   // zero-region end
    int* rowptr   = (int*)(ws + off); off += 25600;
    int* rowptr2  = (int*)(ws + off); off += 25600;
    int* csrc     = (int*)(ws + off); off += N_EDGES;
    int* cdst     = (int*)(ws + off); off += N_EDGES;
    int* posMap   = (int*)(ws + off); off += N_EDGES;
    __half* wtt   = (__half*)(ws + off); off += 16384;    // enc_w2 perm [1024][32]
    __half* wb1t  = (__half*)(ws + off); off += 16384;    // [256][128]
    __half* wb2t  = (__half*)(ws + off); off += 131072;   // [256][1024]
    __half* w1t   = (__half*)(ws + off); off += 256;      // [32 j][16 k]
    float* wa1    = ws + off; off += 128;
    float* wd1    = ws + off; off += 128;
    float* wa2    = ws + off; off += 1024;
    float* wd2    = ws + off; off += 1024;
    float* esb2   = ws + off; off += 100000;   // layer-2 es (atomic-accumulated)
    float* edb2   = ws + off; off += 100000;   // layer-2 ed

    const int GBT = 3328;   // T-gemm: 8 xcd x 13 ygroups x 32 strips
    const int GBO = 800;    // out-256 gemms: 8 xcd x 4 strips x 25 yhi (y>=196 early-exit)

    // ---- CSR build ----
    hipMemsetAsync(deg, 0, 4 * 25600 * sizeof(int), stream);
    hipMemsetAsync(esb2, 0, 2 * 100000 * sizeof(float), stream);
    k_deg2<<<(N_EDGES + 255) / 256, 256, 0, stream>>>(edge_idx, deg, deg2);
    k_scan2<<<2, 1024, 0, stream>>>(deg, rowptr, deg2, rowptr2);
    k_scatter2<<<(N_EDGES + 255) / 256, 256, 0, stream>>>(edge_idx, edge_attr, rowptr, rowptr2,
                                                          cursor, cursor2, csrc, cdst, posMap, eaP);

    // ---- merged weight prep ----
    k_prep<<<4412, 256, 0, stream>>>(enc_w2, gat1_w, gat2_w, gat1_asrc, gat1_adst,
                                     gat2_asrc, gat2_adst, x, enc_b2, enc_w1,
                                     wtt, wb1t, wb2t, wa1, wd1, wa2, wd2, xf, xb, w1t);

    // ---- NNConv ----
    k_gemT<<<GBT, 256, 0, stream>>>(xf, wtt, T16);
    k_msg3<<<(N_NODES + 3) / 4, 256, 0, stream>>>(rowptr2, posMap, eaP,
                                                  w1t, enc_b1, T16, xb, msgE);
    k_h0e<<<(N_NODES + 7) / 8, 256, 0, stream>>>(x, root_w, nn_bias, msgE, rowptr,
                                                 wa1, wd1, h0f, esb, edb);

    // ---- GAT layer 1 (es/ed for layer 2 fused into GEMM epilogue) ----
    k_agg1<<<(N_NODES + 3) / 4, 256, 0, stream>>>(rowptr, csrc, esb, edb, h0f, agg0f);
    k_gemmo<128, __half, true><<<GBO, 256, 0, stream>>>(agg0f, wb1t, gat1_b, h1f,
                                                        wa2, wd2, esb2, edb2);

    // ---- GAT layer 2 ----
    k_agg2<<<(N_NODES + 3) / 4, 256, 0, stream>>>(rowptr, csrc, esb2, edb2, h1f, agg1f);
    k_gemmo<1024, float, false><<<GBO, 256, 0, stream>>>(agg1f, wb2t, gat2_b, h2,
                                                         nullptr, nullptr, nullptr, nullptr);

    // ---- heads ----
    hipMemsetAsync(pooled, 0, (NGRAPH * 256 + NGRAPH) * sizeof(float), stream);
    k_wirepool<<<KWIRE / 4 + (N_NODES + POOL_NB - 1) / POOL_NB, 256, 0, stream>>>(
        wire_mask, h2, wire_w, wire_b, batch, out, pooled, gcnt);
    k_act<<<NGRAPH * NACT / 4, 256, 0, stream>>>(pooled, gcnt, act_w, act_b, out);
}

// Round 40
// 394.471 us; speedup vs baseline: 1.0124x; 1.0124x over previous
//
#include <hip/hip_runtime.h>
#include <hip/hip_fp16.h>

#define N_NODES 25000
#define M_PAD   25024            // multiple of 16 (1564 tiles)
#define N_TILES 1564
#define N_EDGES 300000
#define IN_DIM  32
#define EDFD    16
#define HIDD    256
#define HEADS   4
#define NACT    16
#define NGRAPH  64
#define KWIRE   1024
#define POOL_NB 64
#define LOG2E   1.44269504088896f

typedef _Float16 half8v __attribute__((ext_vector_type(8)));
typedef __attribute__((ext_vector_type(4))) float f32x4;

// ---------------------------------------------------------------- helpers
__device__ __forceinline__ float leaky(float v) { return v > 0.f ? v : 0.2f * v; }
__device__ __forceinline__ float fexp2(float v) { return __builtin_amdgcn_exp2f(v); }  // raw v_exp_f32

// ---------------------------------------------------------------- CSR build (both directions)
__global__ __launch_bounds__(256) void k_deg2(const int* __restrict__ ei,
                                              int* __restrict__ deg,
                                              int* __restrict__ deg2) {
    int e = blockIdx.x * 256 + threadIdx.x;
    if (e >= N_EDGES) return;
    atomicAdd(&deg[ei[N_EDGES + e]], 1);
    atomicAdd(&deg2[ei[e]], 1);
}

// parallel exclusive scan: 1024 threads, 25 elems/thread, Hillis-Steele tree in LDS
__global__ __launch_bounds__(1024) void k_scan2(const int* __restrict__ degA, int* __restrict__ rpA,
                                                const int* __restrict__ degB, int* __restrict__ rpB) {
    const int* deg = blockIdx.x ? degB : degA;
    int* rowptr    = blockIdx.x ? rpB : rpA;
    __shared__ int part[1024];
    int t = threadIdx.x;
    const int CH = 25;                         // 1024*25 = 25600 >= 25001
    int base = t * CH;
    int s = 0;
    for (int i = 0; i < CH; ++i) {
        int idx = base + i;
        if (idx < N_NODES) s += deg[idx];
    }
    part[t] = s;
    __syncthreads();
    #pragma unroll
    for (int off = 1; off < 1024; off <<= 1) { // inclusive scan, log steps
        int v = (t >= off) ? part[t - off] : 0;
        __syncthreads();
        part[t] += v;
        __syncthreads();
    }
    int run = (t == 0) ? 0 : part[t - 1];      // exclusive prefix for this chunk
    for (int i = 0; i < CH; ++i) {
        int idx = base + i;
        if (idx < N_NODES) { rowptr[idx] = run; run += deg[idx]; }
    }
    if (N_NODES >= base && N_NODES < base + CH) rowptr[N_NODES] = run;
}

// scatter + permute edge_attr into src-CSR order (fp16) + dst-CSR position map
__global__ __launch_bounds__(256) void k_scatter2(const int* __restrict__ ei,
                                                  const float* __restrict__ ea,
                                                  const int* __restrict__ rowptr,
                                                  const int* __restrict__ rowptr2,
                                                  int* __restrict__ cursor,
                                                  int* __restrict__ cursor2,
                                                  int* __restrict__ csrc,
                                                  int* __restrict__ cdst,
                                                  int* __restrict__ posMap,
                                                  __half* __restrict__ eaP) {
    int e = blockIdx.x * 256 + threadIdx.x;
    if (e >= N_EDGES) return;
    int src = ei[e], dst = ei[N_EDGES + e];
    int p1 = atomicAdd(&cursor[dst], 1);
    int r1 = rowptr[dst] + p1;
    csrc[r1] = src;
    int p2 = atomicAdd(&cursor2[src], 1);
    int r2 = rowptr2[src] + p2;
    cdst[r2] = dst;
    posMap[r2] = r1;                             // where this edge's msg lands (dst-CSR)
    const float4* src4 = (const float4*)(ea + (size_t)e * EDFD);
    __half2* dp = (__half2*)(eaP + (size_t)r2 * EDFD);
    #pragma unroll
    for (int q = 0; q < EDFD / 4; ++q) {
        float4 v = src4[q];
        dp[q * 2]     = __float22half2_rn(make_float2(v.x, v.y));
        dp[q * 2 + 1] = __float22half2_rn(make_float2(v.z, v.w));
    }
}

// ---------------------------------------------------------------- merged weight prep
// block ranges: [0,128) w2perm | [128,256) wb1 | [256,1280) wb2 | [1280,4405) xcvt
//               4405 wa1 | [4406,4410) wa2 | [4410,4412) w1t
// wa*/wd* prescaled by LOG2E so agg kernels can use raw v_exp_f32 (leaky is pos-homogeneous).
__global__ __launch_bounds__(256) void k_prep(const float* __restrict__ w2,
                                              const float* __restrict__ W1,
                                              const float* __restrict__ W2,
                                              const float* __restrict__ a1s,
                                              const float* __restrict__ a1d,
                                              const float* __restrict__ a2s,
                                              const float* __restrict__ a2d,
                                              const float* __restrict__ x,
                                              const float* __restrict__ b2,
                                              const float* __restrict__ w1,
                                              __half* __restrict__ wtt,
                                              __half* __restrict__ wb1,
                                              __half* __restrict__ wb2,
                                              float* __restrict__ wa1,
                                              float* __restrict__ wd1,
                                              float* __restrict__ wa2,
                                              float* __restrict__ wd2,
                                              __half* __restrict__ xf,
                                              float* __restrict__ xb,
                                              __half* __restrict__ w1t) {
    int bid = blockIdx.x, t = threadIdx.x;
    if (bid < 128) {                             // enc_w2 perm: wtt[co][i]
        int idx = bid * 256 + t;                 // co*32+i
        int co = idx >> 5, i = idx & 31;
        wtt[idx] = __float2half(w2[(co >> 5) * 1024 + i * 32 + (co & 31)]);
    } else if (bid < 256) {                      // wb1[d][k], k=h*32+i
        int idx = (bid - 128) * 256 + t;
        int d = idx >> 7, k = idx & 127;
        int h = k >> 5, i = k & 31;
        wb1[idx] = __float2half(0.25f * W1[i * 1024 + h * 256 + d]);
    } else if (bid < 1280) {                     // wb2[d][k], k=h*256+i
        int idx = (bid - 256) * 256 + t;
        int d = idx >> 10, k = idx & 1023;
        int h = k >> 8, i = k & 255;
        wb2[idx] = __float2half(0.25f * W2[i * 1024 + h * 256 + d]);
    } else if (bid < 4405) {                     // xcvt
        int idx = (bid - 1280) * 256 + t;
        if (idx >= N_NODES * 32) return;
        int n = idx >> 5, o = idx & 31;
        xf[idx] = __float2half(x[idx]);
        float s = 0.f;
        for (int i = 0; i < 32; ++i) s += x[n * 32 + i] * b2[i * 32 + o];
        xb[idx] = s;
    } else if (bid == 4405) {                    // wa1/wd1 (128 lanes), log2e-prescaled
        if (t >= 128) return;
        int h = t >> 5, i = t & 31;
        float s = 0.f, sd = 0.f;
        for (int d = 0; d < 256; ++d) {
            float w = W1[i * 1024 + h * 256 + d];
            s  += w * a1s[h * 256 + d];
            sd += w * a1d[h * 256 + d];
        }
        wa1[t] = s * LOG2E; wd1[t] = sd * LOG2E;
    } else if (bid < 4410) {                     // wa2/wd2, log2e-prescaled
        int idx = (bid - 4406) * 256 + t;        // h*256+i
        if (idx >= 1024) return;
        int h = idx >> 8, i = idx & 255;
        float s = 0.f, sd = 0.f;
        for (int d = 0; d < 256; ++d) {
            float w = W2[i * 1024 + h * 256 + d];
            s  += w * a2s[h * 256 + d];
            sd += w * a2d[h * 256 + d];
        }
        wa2[idx] = s * LOG2E; wd2[idx] = sd * LOG2E;
    } else {                                     // w1t[j][k] = fp16(w1[k*32+j])
        int idx = (bid - 4410) * 256 + t;        // j*16+k
        if (idx >= 32 * EDFD) return;
        int j = idx >> 4, k = idx & 15;
        w1t[idx] = __float2half(w1[k * 32 + j]);
    }
}

// ---------------------------------------------------------------- NNConv via MFMA
// wave per src: msgE[16 edges,32] = relu(eaP[16,16] @ w1 + b1) @ T[src] + xb[src]
__global__ __launch_bounds__(256) void k_msg3(const int* __restrict__ rowptr2,
                                              const int* __restrict__ posMap,
                                              const __half* __restrict__ eaP,
                                              const __half* __restrict__ w1t,
                                              const float* __restrict__ b1,
                                              const __half* __restrict__ T,
                                              const float* __restrict__ xb,
                                              __half* __restrict__ msgE) {
    int wv = threadIdx.x >> 6, lane = threadIdx.x & 63;
    int src = blockIdx.x * 4 + wv;
    if (src >= N_NODES) return;
    int r0 = rowptr2[src], r1 = rowptr2[src + 1];
    if (r0 == r1) return;
    int lr = lane & 15, lk = (lane >> 4) * 8;

    // B fragments from T[src] (layout [j*32+o]): col lr (B0) and 16+lr (B1), k = lk..lk+7
    half8v bf0, bf1;
    const __half* Tp = T + (size_t)src * 1024;
    #pragma unroll
    for (int q = 0; q < 8; ++q) {
        bf0[q] = (_Float16)__half2float(Tp[(lk + q) * 32 + lr]);
        bf1[q] = (_Float16)__half2float(Tp[(lk + q) * 32 + 16 + lr]);
    }

    // w1 rows lk..lk+7 (fp16, 16 k each) held in registers
    __half2 w1r[8][EDFD / 2];
    #pragma unroll
    for (int q = 0; q < 8; ++q) {
        const __half2* wp = (const __half2*)(w1t + (lk + q) * EDFD);
        #pragma unroll
        for (int k2 = 0; k2 < EDFD / 2; ++k2) w1r[q][k2] = wp[k2];
    }
    float b1r[8];
    #pragma unroll
    for (int q = 0; q < 8; ++q) b1r[q] = b1[lk + q];

    float xb0 = xb[src * 32 + lr], xb1 = xb[src * 32 + 16 + lr];
    int rbase = (lane >> 4) * 4;

    for (int t0 = r0; t0 < r1; t0 += 16) {
        int e = t0 + lr;
        bool ok = (e < r1);
        // MLP for edge e, outputs j = lk..lk+7
        half8v afr;
        if (ok) {
            const __half2* ep = (const __half2*)(eaP + (size_t)e * EDFD);
            __half2 ea2[EDFD / 2];
            #pragma unroll
            for (int k2 = 0; k2 < EDFD / 2; ++k2) ea2[k2] = ep[k2];
            #pragma unroll
            for (int q = 0; q < 8; ++q) {
                float s = b1r[q];
                #pragma unroll
                for (int k2 = 0; k2 < EDFD / 2; ++k2) {
                    float2 v = __half22float2(ea2[k2]);
                    float2 w = __half22float2(w1r[q][k2]);
                    s += v.x * w.x + v.y * w.y;
                }
                afr[q] = (_Float16)fmaxf(s, 0.f);
            }
        } else {
            #pragma unroll
            for (int q = 0; q < 8; ++q) afr[q] = (_Float16)0.f;
        }
        f32x4 c0 = {0.f, 0.f, 0.f, 0.f}, c1 = {0.f, 0.f, 0.f, 0.f};
        c0 = __builtin_amdgcn_mfma_f32_16x16x32_f16(afr, bf0, c0, 0, 0, 0);
        c1 = __builtin_amdgcn_mfma_f32_16x16x32_f16(afr, bf1, c1, 0, 0, 0);
        #pragma unroll
        for (int r = 0; r < 4; ++r) {
            int er = t0 + rbase + r;
            if (er < r1) {
                int pm = posMap[er];
                msgE[(size_t)pm * 32 + lr]      = __float2half(c0[r] + xb0);
                msgE[(size_t)pm * 32 + 16 + lr] = __float2half(c1[r] + xb1);
            }
        }
    }
}

// h0 = relu(sum(msgE)/deg + x@root_w + bias) -> fp16, fused layer1 es/ed (log2-space)
__global__ __launch_bounds__(256) void k_h0e(const float* __restrict__ x,
                                             const float* __restrict__ root_w,
                                             const float* __restrict__ nn_bias,
                                             const __half* __restrict__ msgE,
                                             const int* __restrict__ rowptr,
                                             const float* __restrict__ wa,
                                             const float* __restrict__ wd,
                                             __half* __restrict__ h0f,
                                             float* __restrict__ es,
                                             float* __restrict__ ed) {
    int t = threadIdx.x;
    int ng = t >> 5, o = t & 31;
    int n = blockIdx.x * 8 + ng;
    if (n >= N_NODES) return;
    float s = nn_bias[o];
    for (int k = 0; k < IN_DIM; ++k) s += x[n * IN_DIM + k] * root_w[k * 32 + o];
    int r0 = rowptr[n], r1 = rowptr[n + 1];
    float aggv = 0.f;
    for (int r = r0; r < r1; ++r)
        aggv += __half2float(msgE[(size_t)r * 32 + o]);  // sequential 64B reads per group
    float c = fmaxf((float)(r1 - r0), 1.f);
    s += aggv / c;
    float v = fmaxf(s, 0.f);
    h0f[n * IN_DIM + o] = __float2half(v);
    #pragma unroll
    for (int h = 0; h < 4; ++h) {
        float ss = v * wa[h * 32 + o];
        float dd = v * wd[h * 32 + o];
        #pragma unroll
        for (int off = 16; off; off >>= 1) {
            ss += __shfl_down(ss, off, 32);
            dd += __shfl_down(dd, off, 32);
        }
        if (o == 0) { es[n * 4 + h] = ss; ed[n * 4 + h] = dd; }
    }
}

// ---------------------------------------------------------------- GEMM 1: T = xf @ wtt^T, out [M,1024] fp16
__global__ __launch_bounds__(256, 2) void k_gemT(const __half* __restrict__ A,
                                                 const __half* __restrict__ Wt,
                                                 __half* __restrict__ C) {
    __shared__ __half cst[4][16 * 36];
    int t = threadIdx.x, wid = t >> 6, lane = t & 63;
    int lr = lane & 15, lk = (lane >> 4) * 8;

    int bid = blockIdx.x;
    int xcd = bid & 7, j = bid >> 3;
    int sx = j & 31;
    int y = ((j >> 5) << 3) | xcd;            // 0..103
    int n0 = sx * 32;

    half8v bfr[2];
    #pragma unroll
    for (int c = 0; c < 2; ++c)
        bfr[c] = *(const half8v*)(Wt + (size_t)(n0 + c * 16 + lr) * 32 + lk);

    int tb = (y * 4 + wid) * 4;
    for (int pp = 0; pp < 4; pp += 2) {
        int tA = tb + pp;
        if (tA >= N_TILES) break;
        int mA = tA * 16, mB = mA + 16;
        half8v aA = *(const half8v*)(A + (size_t)(mA + lr) * 32 + lk);
        half8v aB = *(const half8v*)(A + (size_t)(mB + lr) * 32 + lk);
        f32x4 acc[2][2];
        #pragma unroll
        for (int i = 0; i < 2; ++i)
            #pragma unroll
            for (int c = 0; c < 2; ++c)
                acc[i][c] = (f32x4){0.f, 0.f, 0.f, 0.f};
        acc[0][0] = __builtin_amdgcn_mfma_f32_16x16x32_f16(aA, bfr[0], acc[0][0], 0, 0, 0);
        acc[0][1] = __builtin_amdgcn_mfma_f32_16x16x32_f16(aA, bfr[1], acc[0][1], 0, 0, 0);
        acc[1][0] = __builtin_amdgcn_mfma_f32_16x16x32_f16(aB, bfr[0], acc[1][0], 0, 0, 0);
        acc[1][1] = __builtin_amdgcn_mfma_f32_16x16x32_f16(aB, bfr[1], acc[1][1], 0, 0, 0);

        int rbase = (lane >> 4) * 4;
        #pragma unroll
        for (int ti = 0; ti < 2; ++ti) {
            #pragma unroll
            for (int c = 0; c < 2; ++c)
                #pragma unroll
                for (int r = 0; r < 4; ++r)
                    cst[wid][(rbase + r) * 36 + c * 16 + lr] = __float2half(acc[ti][c][r]);
            int m0 = ti ? mB : mA;
            #pragma unroll
            for (int p = 0; p < 2; ++p) {
                int row = p * 8 + (lane >> 3), hb = lane & 7;
                float2 v = *(const float2*)((const char*)&cst[wid][0] + row * 72 + hb * 8);
                *(float2*)((char*)C + ((size_t)(m0 + row) * 1024 + n0) * 2 + hb * 8) = v;
            }
        }
    }
}

// ---------------------------------------------------------------- GEMM 2: head-mean-folded, out [M,256]
// block = 8 row-tiles x 64 cols; wave owns 2 tiles; A-loads hoisted; A re-read 4x.
// Staging via global_load_lds (linear LDS dest, pre-swizzled global src; same byte placement).
// FUSE_ED: accumulate layer-2 attention scalars es/ed from epilogue values (atomic partials).
template <int K, typename OT, bool FUSE_ED>
__global__ __launch_bounds__(256, 3) void k_gemmo(const __half* __restrict__ A,
                                                  const __half* __restrict__ Wt,
                                                  const float* __restrict__ bias,
                                                  OT* __restrict__ C,
                                                  const float* __restrict__ wa,
                                                  const float* __restrict__ wd,
                                                  float* __restrict__ es,
                                                  float* __restrict__ ed) {
    constexpr int CK  = 128;                    // LDS chunk K-extent
    constexpr int KC  = K / CK;
    constexpr int KSC = CK / 32;
    constexpr int CB  = CK * 2;                 // bytes per LDS col (256)
    __shared__ __half bs[2][64 * CK];           // 64 cols x CK (16KB per buffer)
    __shared__ float cst[4][16 * 36];
    int t = threadIdx.x, wid = t >> 6, lane = t & 63;
    int lr = lane & 15, lk = (lane >> 4) * 8;

    int bid = blockIdx.x;
    int xcd = bid & 7, rest = bid >> 3;
    int strip = rest & 3, yhi = rest >> 2;
    int y = yhi * 8 + xcd;                      // row-group (8 tiles); same y -> same XCD
    if (y >= 196) return;                       // block-uniform early exit (196*8=1568>=1564)
    int n0 = strip * 64;
    float bv[4];
    #pragma unroll
    for (int c = 0; c < 4; ++c) bv[c] = bias[n0 + c * 16 + lr];
    int tb = y * 8 + wid * 2;                   // wave's first tile
    int tA0 = tb     < N_TILES ? tb     : N_TILES - 1;   // clamped (no barrier divergence)
    int tA1 = tb + 1 < N_TILES ? tb + 1 : N_TILES - 1;
    const int swz = (lr & 7) << 4;

    f32x4 acc[2][4];                            // [tile][colblock]
    #pragma unroll
    for (int i = 0; i < 2; ++i)
        #pragma unroll
        for (int c = 0; c < 4; ++c)
            acc[i][c] = (f32x4){0.f, 0.f, 0.f, 0.f};

    // async stage: LDS[lo] = Wt[g(lo ^ swz(col))] -- identical placement to reg-staged XOR write
    #define STAGE_CHUNK(BUF, KCN)                                                              \
        _Pragma("unroll")                                                                      \
        for (int it = 0; it < (64 * CB) / (256 * 16); ++it) {                                  \
            int lo = it * 4096 + wid * 1024 + lane * 16;                                       \
            int col = lo >> 8;                                                                 \
            int go = lo ^ ((col & 7) << 4);                                                    \
            const char* sp_ = (const char*)Wt + ((size_t)(n0 + col) * K + (KCN) * CK) * 2      \
                              + (go & (CB - 1));                                               \
            __builtin_amdgcn_global_load_lds(                                                  \
                (const __attribute__((address_space(1))) void*)sp_,                            \
                (__attribute__((address_space(3))) void*)((char*)bs[BUF] + it * 4096 + wid * 1024), \
                16, 0, 0);                                                                     \
        }

    STAGE_CHUNK(0, 0)
    __syncthreads();

    const __half* pA0 = A + (size_t)(tA0 * 16 + lr) * K + lk;
    const __half* pA1 = A + (size_t)(tA1 * 16 + lr) * K + lk;

    for (int kc = 0; kc < KC; ++kc) {
        int cur = kc & 1;
        if (kc + 1 < KC) {
            STAGE_CHUNK(cur ^ 1, kc + 1)
        }
        // hoist all A fragments for this chunk (8 outstanding 16B loads)
        half8v aH0[KSC], aH1[KSC];
        #pragma unroll
        for (int ks = 0; ks < KSC; ++ks) {
            aH0[ks] = *(const half8v*)(pA0 + kc * CK + ks * 32);
            aH1[ks] = *(const half8v*)(pA1 + kc * CK + ks * 32);
        }
        #pragma unroll
        for (int ks = 0; ks < KSC; ++ks) {
            #pragma unroll
            for (int c = 0; c < 4; ++c) {
                half8v b = *(const half8v*)((const char*)bs[cur] +
                            (((c * 16 + lr) * CB + lk * 2 + ks * 64) ^ swz));
                acc[0][c] = __builtin_amdgcn_mfma_f32_16x16x32_f16(aH0[ks], b, acc[0][c], 0, 0, 0);
                acc[1][c] = __builtin_amdgcn_mfma_f32_16x16x32_f16(aH1[ks], b, acc[1][c], 0, 0, 0);
            }
        }
        if (kc + 1 < KC) __syncthreads();
    }
    #undef STAGE_CHUNK

    int rbase = (lane >> 4) * 4;
    #pragma unroll
    for (int ti = 0; ti < 2; ++ti) {
        if (tb + ti >= N_TILES) break;
        int m0 = (tb + ti) * 16;
        int row = lane >> 2, cg = lane & 3;     // 16 rows x 4 col-groups of 8
        #pragma unroll
        for (int half = 0; half < 2; ++half) {
            #pragma unroll
            for (int c = 0; c < 2; ++c)
                #pragma unroll
                for (int r = 0; r < 4; ++r)
                    cst[wid][(rbase + r) * 36 + c * 16 + lr] =
                        fmaxf(acc[ti][half * 2 + c][r] + bv[half * 2 + c], 0.f);
            int colb = n0 + half * 32;
            const float* sp = &cst[wid][row * 36 + cg * 8];
            if constexpr (sizeof(OT) == 2) {
                __half2 o0 = __float22half2_rn(make_float2(sp[0], sp[1]));
                __half2 o1 = __float22half2_rn(make_float2(sp[2], sp[3]));
                __half2 o2 = __float22half2_rn(make_float2(sp[4], sp[5]));
                __half2 o3 = __float22half2_rn(make_float2(sp[6], sp[7]));
                float4 v = make_float4(__uint_as_float(*(unsigned*)&o0), __uint_as_float(*(unsigned*)&o1),
                                       __uint_as_float(*(unsigned*)&o2), __uint_as_float(*(unsigned*)&o3));
                *(float4*)((__half*)C + (size_t)(m0 + row) * 256 + colb + cg * 8) = v;
            } else {
                float4 v0 = make_float4(sp[0], sp[1], sp[2], sp[3]);
                float4 v1 = make_float4(sp[4], sp[5], sp[6], sp[7]);
                float* cp = (float*)C + (size_t)(m0 + row) * 256 + colb + cg * 8;
                *(float4*)cp = v0;
                *(float4*)(cp + 4) = v1;
            }
            if constexpr (FUSE_ED) {
                int rowg = m0 + row;
                #pragma unroll
                for (int h = 0; h < 4; ++h) {
                    float pes = 0.f, ped = 0.f;
                    #pragma unroll
                    for (int d = 0; d < 8; ++d) {
                        float vv = sp[d];
                        pes += vv * wa[h * 256 + colb + cg * 8 + d];
                        ped += vv * wd[h * 256 + colb + cg * 8 + d];
                    }
                    // reduce across the 4 cg lanes (consecutive lanes 4*row..4*row+3)
                    pes += __shfl_down(pes, 1, 4); pes += __shfl_down(pes, 2, 4);
                    ped += __shfl_down(ped, 1, 4); ped += __shfl_down(ped, 2, 4);
                    if (cg == 0 && rowg < N_NODES) {
                        atomicAdd(&es[rowg * 4 + h], pes);
                        atomicAdd(&ed[rowg * 4 + h], ped);
                    }
                }
            }
        }
    }
}

// ---------------------------------------------------------------- aggregation (softmax fused; raw v_exp_f32)
__global__ __launch_bounds__(256) void k_agg1(const int* __restrict__ rowptr,
                                              const int* __restrict__ csrc,
                                              const float* __restrict__ es,
                                              const float* __restrict__ ed,
                                              const __half* __restrict__ h0f,
                                              __half* __restrict__ agg0) {
    int dst = blockIdx.x * 4 + (threadIdx.x >> 6);
    if (dst >= N_NODES) return;
    int lane = threadIdx.x & 63;
    int h = lane >> 4, i2 = lane & 15;
    float edv = ed[dst * 4 + h];
    float vself = leaky(es[dst * 4 + h] + edv);   // shift = self-loop score (w_self = 1)
    float dn = 1.f;
    int r0 = rowptr[dst], r1 = rowptr[dst + 1];

    __half2 hv = *(const __half2*)(h0f + (size_t)dst * 32 + i2 * 2);
    float2 f = __half22float2(hv);
    float ax = f.x, ay = f.y;
    for (int r = r0; r < r1; ++r) {
        int src = csrc[r];
        float w = fexp2(leaky(es[src * 4 + h] + edv) - vself);
        dn += w;
        __half2 sv = *(const __half2*)(h0f + (size_t)src * 32 + i2 * 2);
        float2 g = __half22float2(sv);
        ax += w * g.x; ay += w * g.y;
    }
    float inv = 1.f / (dn + 1e-16f);
    *(__half2*)(agg0 + (size_t)dst * 128 + h * 32 + i2 * 2) =
        __float22half2_rn(make_float2(ax * inv, ay * inv));
}

__global__ __launch_bounds__(256) void k_agg2(const int* __restrict__ rowptr,
                                              const int* __restrict__ csrc,
                                              const float* __restrict__ es,
                                              const float* __restrict__ ed,
                                              const __half* __restrict__ h1f,
                                              __half* __restrict__ agg1) {
    int dst = blockIdx.x * 4 + (threadIdx.x >> 6);
    if (dst >= N_NODES) return;
    int lane = threadIdx.x & 63;
    float vs[4], edv[4], dn[4];
    float acc[4][4];
    {
        float2 q = *(const float2*)(h1f + (size_t)dst * 256 + lane * 4);
        const __half2* hq = (const __half2*)&q;
        float2 f0 = __half22float2(hq[0]), f1 = __half22float2(hq[1]);
        #pragma unroll
        for (int h = 0; h < 4; ++h) {
            edv[h] = ed[dst * 4 + h];
            vs[h] = leaky(es[dst * 4 + h] + edv[h]);
            dn[h] = 1.f;                          // w_self = 1 under self-loop shift
            acc[h][0] = f0.x; acc[h][1] = f0.y;
            acc[h][2] = f1.x; acc[h][3] = f1.y;
        }
    }
    int r0 = rowptr[dst], r1 = rowptr[dst + 1];
    for (int r = r0; r < r1; ++r) {
        int src = csrc[r];
        float4 esv = *(const float4*)(es + (size_t)src * 4);
        float w0 = fexp2(leaky(esv.x + edv[0]) - vs[0]);
        float w1 = fexp2(leaky(esv.y + edv[1]) - vs[1]);
        float w2 = fexp2(leaky(esv.z + edv[2]) - vs[2]);
        float w3 = fexp2(leaky(esv.w + edv[3]) - vs[3]);
        dn[0] += w0; dn[1] += w1; dn[2] += w2; dn[3] += w3;
        float2 q = *(const float2*)(h1f + (size_t)src * 256 + lane * 4);
        const __half2* hq = (const __half2*)&q;
        float2 f0 = __half22float2(hq[0]), f1 = __half22float2(hq[1]);
        acc[0][0] += w0 * f0.x; acc[0][1] += w0 * f0.y; acc[0][2] += w0 * f1.x; acc[0][3] += w0 * f1.y;
        acc[1][0] += w1 * f0.x; acc[1][1] += w1 * f0.y; acc[1][2] += w1 * f1.x; acc[1][3] += w1 * f1.y;
        acc[2][0] += w2 * f0.x; acc[2][1] += w2 * f0.y; acc[2][2] += w2 * f1.x; acc[2][3] += w2 * f1.y;
        acc[3][0] += w3 * f0.x; acc[3][1] += w3 * f0.y; acc[3][2] += w3 * f1.x; acc[3][3] += w3 * f1.y;
    }
    #pragma unroll
    for (int h = 0; h < 4; ++h) {
        float inv = 1.f / (dn[h] + 1e-16f);
        __half2 o0 = __float22half2_rn(make_float2(acc[h][0] * inv, acc[h][1] * inv));
        __half2 o1 = __float22half2_rn(make_float2(acc[h][2] * inv, acc[h][3] * inv));
        __half2* op = (__half2*)(agg1 + (size_t)dst * 1024 + h * 256 + lane * 4);
        op[0] = o0; op[1] = o1;
    }
}

// ---------------------------------------------------------------- heads (wire + pool merged)
__global__ __launch_bounds__(256) void k_wirepool(const int* __restrict__ wm,
                                                  const float* __restrict__ h2,
                                                  const float* __restrict__ ww,
                                                  const float* __restrict__ wb,
                                                  const int* __restrict__ batch,
                                                  float* __restrict__ out,
                                                  float* __restrict__ pooled,
                                                  float* __restrict__ gcnt) {
    int bid = blockIdx.x;
    if (bid < KWIRE / 4) {                       // wire head
        int k = bid * 4 + (threadIdx.x >> 6);
        int lane = threadIdx.x & 63;
        int n = wm[k];
        float s = 0.f;
        for (int d = lane; d < 256; d += 64) s += h2[(size_t)n * 256 + d] * ww[d];
        #pragma unroll
        for (int off = 32; off; off >>= 1) s += __shfl_down(s, off);
        if (lane == 0) out[k] = s + wb[0];
        return;
    }
    // segmented pooling
    int n0 = (bid - KWIRE / 4) * POOL_NB;
    int n1 = n0 + POOL_NB; if (n1 > N_NODES) n1 = N_NODES;
    int d = threadIdx.x;
    int cur = batch[n0];
    float acc = 0.f, cnt = 0.f;
    for (int n = n0; n < n1; ++n) {
        int g = batch[n];
        if (g != cur) {
            atomicAdd(&pooled[cur * 256 + d], acc);
            if (d == 0) atomicAdd(&gcnt[cur], cnt);
            acc = 0.f; cnt = 0.f; cur = g;
        }
        acc += h2[(size_t)n * 256 + d];
        cnt += 1.f;
    }
    atomicAdd(&pooled[cur * 256 + d], acc);
    if (d == 0) atomicAdd(&gcnt[cur], cnt);
}

__global__ __launch_bounds__(256) void k_act(const float* __restrict__ pooled,
                                             const float* __restrict__ gcnt,
                                             const float* __restrict__ aw,
                                             const float* __restrict__ ab,
                                             float* __restrict__ out) {
    int u = blockIdx.x * 4 + (threadIdx.x >> 6);
    int lane = threadIdx.x & 63;
    if (u >= NGRAPH * NACT) return;
    int g = u >> 4, a = u & 15;
    float c = fmaxf(gcnt[g], 1.f);
    float s = 0.f;
    for (int d = lane; d < 256; d += 64) s += pooled[g * 256 + d] * aw[d * 16 + a];
    #pragma unroll
    for (int off = 32; off; off >>= 1) s += __shfl_down(s, off);
    if (lane == 0) out[KWIRE + u] = s / c + ab[a];
}

// ---------------------------------------------------------------- launch
extern "C" void kernel_launch(void* const* d_in, const int* in_sizes, int n_in,
                              void* d_out, int out_size, void* d_ws, size_t ws_size,
                              hipStream_t stream) {
    const float* x        = (const float*)d_in[0];
    const float* edge_attr= (const float*)d_in[1];
    const int*   wire_mask= (const int*)d_in[2];
    const int*   edge_idx = (const int*)d_in[3];
    const int*   batch    = (const int*)d_in[4];
    const float* enc_w1   = (const float*)d_in[5];
    const float* enc_b1   = (const float*)d_in[6];
    const float* enc_w2   = (const float*)d_in[7];
    const float* enc_b2   = (const float*)d_in[8];
    const float* root_w   = (const float*)d_in[9];
    const float* nn_bias  = (const float*)d_in[10];
    const float* gat1_w   = (const float*)d_in[11];
    const float* gat1_asrc= (const float*)d_in[12];
    const float* gat1_adst= (const float*)d_in[13];
    const float* gat1_b   = (const float*)d_in[14];
    const float* gat2_w   = (const float*)d_in[15];
    const float* gat2_asrc= (const float*)d_in[16];
    const float* gat2_adst= (const float*)d_in[17];
    const float* gat2_b   = (const float*)d_in[18];
    const float* wire_w   = (const float*)d_in[19];
    const float* wire_b   = (const float*)d_in[20];
    const float* act_w    = (const float*)d_in[21];
    const float* act_b    = (const float*)d_in[22];
    float* out = (float*)d_out;

    float* ws = (float*)d_ws;
    size_t off = 0;
    __half* T16   = (__half*)(ws + off); off += (size_t)M_PAD * 1024 / 2;
    __half* agg1f = (__half*)(ws + off); off += (size_t)M_PAD * 1024 / 2;
    __half* agg0f = (__half*)(ws + off); off += (size_t)M_PAD * 128 / 2;
    __half* h0f   = (__half*)(ws + off); off += (size_t)M_PAD * 32 / 2;
    __half* h1f   = (__half*)(ws + off); off += (size_t)M_PAD * 256 / 2;
    __half* xf    = (__half*)(ws + off); off += (size_t)M_PAD * 32 / 2;
    __half* eaP   = (__half*)(ws + off); off += (size_t)N_EDGES * EDFD / 2;
    __half* msgE  = (__half*)(ws + off); off += (size_t)N_EDGES * 32 / 2;
    float* xb     = ws + off; off += 800000;
    float* esb    = ws + off; off += 100000;
    float* edb    = ws + off; off += 100000;
    float* h2     = ws + off; off += (size_t)M_PAD * 256;
    float* pooled = ws + off; off += NGRAPH * 256;
    float* gcnt   = ws + off; off += NGRAPH;
    int* deg      = (int*)(ws + off); off += 25600;   // zero-region start
    int* deg2     = (int*)(ws + off); off += 25600;
    int* cursor   = (int*)(ws + off); off += 25600;
    int* cursor2  = (int*)(ws + off); off += 25600;   // zero-region end
    int* rowptr   = (int*)(ws + off); off += 25600;
    int* rowptr2  = (int*)(ws + off); off += 25600;
    int* csrc     = (int*)(ws + off); off += N_EDGES;
    int* cdst     = (int*)(ws + off); off += N_EDGES;
    int* posMap   = (int*)(ws + off); off += N_EDGES;
    __half* wtt   = (__half*)(ws + off); off += 16384;    // enc_w2 perm [1024][32]
    __half* wb1t  = (__half*)(ws + off); off += 16384;    // [256][128]
    __half* wb2t  = (__half*)(ws + off); off += 131072;   // [256][1024]
    __half* w1t   = (__half*)(ws + off); off += 256;      // [32 j][16 k]
    float* wa1    = ws + off; off += 128;
    float* wd1    = ws + off; off += 128;
    float* wa2    = ws + off; off += 1024;
    float* wd2    = ws + off; off += 1024;
    float* esb2   = ws + off; off += 100000;   // layer-2 es (atomic-accumulated)
    float* edb2   = ws + off; off += 100000;   // layer-2 ed

    const int GBT = 3328;   // T-gemm: 8 xcd x 13 ygroups x 32 strips
    const int GBO = 800;    // out-256 gemms: 8 xcd x 4 strips x 25 yhi (y>=196 early-exit)

    // ---- CSR build ----
    hipMemsetAsync(deg, 0, 4 * 25600 * sizeof(int), stream);
    hipMemsetAsync(esb2, 0, 2 * 100000 * sizeof(float), stream);
    k_deg2<<<(N_EDGES + 255) / 256, 256, 0, stream>>>(edge_idx, deg, deg2);
    k_scan2<<<2, 1024, 0, stream>>>(deg, rowptr, deg2, rowptr2);
    k_scatter2<<<(N_EDGES + 255) / 256, 256, 0, stream>>>(edge_idx, edge_attr, rowptr, rowptr2,
                                                          cursor, cursor2, csrc, cdst, posMap, eaP);

    // ---- merged weight prep ----
    k_prep<<<4412, 256, 0, stream>>>(enc_w2, gat1_w, gat2_w, gat1_asrc, gat1_adst,
                                     gat2_asrc, gat2_adst, x, enc_b2, enc_w1,
                                     wtt, wb1t, wb2t, wa1, wd1, wa2, wd2, xf, xb, w1t);

    // ---- NNConv ----
    k_gemT<<<GBT, 256, 0, stream>>>(xf, wtt, T16);
    k_msg3<<<(N_NODES + 3) / 4, 256, 0, stream>>>(rowptr2, posMap, eaP,
                                                  w1t, enc_b1, T16, xb, msgE);
    k_h0e<<<(N_NODES + 7) / 8, 256, 0, stream>>>(x, root_w, nn_bias, msgE, rowptr,
                                                 wa1, wd1, h0f, esb, edb);

    // ---- GAT layer 1 (es/ed for layer 2 fused into GEMM epilogue) ----
    k_agg1<<<(N_NODES + 3) / 4, 256, 0, stream>>>(rowptr, csrc, esb, edb, h0f, agg0f);
    k_gemmo<128, __half, true><<<GBO, 256, 0, stream>>>(agg0f, wb1t, gat1_b, h1f,
                                                        wa2, wd2, esb2, edb2);

    // ---- GAT layer 2 ----
    k_agg2<<<(N_NODES + 3) / 4, 256, 0, stream>>>(rowptr, csrc, esb2, edb2, h1f, agg1f);
    k_gemmo<1024, float, false><<<GBO, 256, 0, stream>>>(agg1f, wb2t, gat2_b, h2,
                                                         nullptr, nullptr, nullptr, nullptr);

    // ---- heads ----
    hipMemsetAsync(pooled, 0, (NGRAPH * 256 + NGRAPH) * sizeof(float), stream);
    k_wirepool<<<KWIRE / 4 + (N_NODES + POOL_NB - 1) / POOL_NB, 256, 0, stream>>>(
        wire_mask, h2, wire_w, wire_b, batch, out, pooled, gcnt);
    k_act<<<NGRAPH * NACT / 4, 256, 0, stream>>>(pooled, gcnt, act_w, act_b, out);
}

// Round 41
// 384.541 us; speedup vs baseline: 1.0385x; 1.0258x over previous
//
#include <hip/hip_runtime.h>
#include <hip/hip_fp16.h>

#define N_NODES 25000
#define M_PAD   25024            // multiple of 16 (1564 tiles)
#define N_TILES 1564
#define N_EDGES 300000
#define IN_DIM  32
#define EDFD    16
#define HIDD    256
#define HEADS   4
#define NACT    16
#define NGRAPH  64
#define KWIRE   1024
#define POOL_NB 64
#define LOG2E   1.44269504088896f

typedef _Float16 half8v __attribute__((ext_vector_type(8)));
typedef __attribute__((ext_vector_type(4))) float f32x4;

// ---------------------------------------------------------------- helpers
__device__ __forceinline__ float leaky(float v) { return v > 0.f ? v : 0.2f * v; }
__device__ __forceinline__ float fexp2(float v) { return __builtin_amdgcn_exp2f(v); }  // raw v_exp_f32

// ---------------------------------------------------------------- CSR build (both directions)
__global__ __launch_bounds__(256) void k_deg2(const int* __restrict__ ei,
                                              int* __restrict__ deg,
                                              int* __restrict__ deg2) {
    int e = blockIdx.x * 256 + threadIdx.x;
    if (e >= N_EDGES) return;
    atomicAdd(&deg[ei[N_EDGES + e]], 1);
    atomicAdd(&deg2[ei[e]], 1);
}

// parallel exclusive scan: 1024 threads, 25 elems/thread, Hillis-Steele tree in LDS
__global__ __launch_bounds__(1024) void k_scan2(const int* __restrict__ degA, int* __restrict__ rpA,
                                                const int* __restrict__ degB, int* __restrict__ rpB) {
    const int* deg = blockIdx.x ? degB : degA;
    int* rowptr    = blockIdx.x ? rpB : rpA;
    __shared__ int part[1024];
    int t = threadIdx.x;
    const int CH = 25;                         // 1024*25 = 25600 >= 25001
    int base = t * CH;
    int s = 0;
    for (int i = 0; i < CH; ++i) {
        int idx = base + i;
        if (idx < N_NODES) s += deg[idx];
    }
    part[t] = s;
    __syncthreads();
    #pragma unroll
    for (int off = 1; off < 1024; off <<= 1) { // inclusive scan, log steps
        int v = (t >= off) ? part[t - off] : 0;
        __syncthreads();
        part[t] += v;
        __syncthreads();
    }
    int run = (t == 0) ? 0 : part[t - 1];      // exclusive prefix for this chunk
    for (int i = 0; i < CH; ++i) {
        int idx = base + i;
        if (idx < N_NODES) { rowptr[idx] = run; run += deg[idx]; }
    }
    if (N_NODES >= base && N_NODES < base + CH) rowptr[N_NODES] = run;
}

// scatter + permute edge_attr into src-CSR order (fp16) + dst-CSR position map
__global__ __launch_bounds__(256) void k_scatter2(const int* __restrict__ ei,
                                                  const float* __restrict__ ea,
                                                  const int* __restrict__ rowptr,
                                                  const int* __restrict__ rowptr2,
                                                  int* __restrict__ cursor,
                                                  int* __restrict__ cursor2,
                                                  int* __restrict__ csrc,
                                                  int* __restrict__ cdst,
                                                  int* __restrict__ posMap,
                                                  __half* __restrict__ eaP) {
    int e = blockIdx.x * 256 + threadIdx.x;
    if (e >= N_EDGES) return;
    int src = ei[e], dst = ei[N_EDGES + e];
    int p1 = atomicAdd(&cursor[dst], 1);
    int r1 = rowptr[dst] + p1;
    csrc[r1] = src;
    int p2 = atomicAdd(&cursor2[src], 1);
    int r2 = rowptr2[src] + p2;
    cdst[r2] = dst;
    posMap[r2] = r1;                             // where this edge's msg lands (dst-CSR)
    const float4* src4 = (const float4*)(ea + (size_t)e * EDFD);
    __half2* dp = (__half2*)(eaP + (size_t)r2 * EDFD);
    #pragma unroll
    for (int q = 0; q < EDFD / 4; ++q) {
        float4 v = src4[q];
        dp[q * 2]     = __float22half2_rn(make_float2(v.x, v.y));
        dp[q * 2 + 1] = __float22half2_rn(make_float2(v.z, v.w));
    }
}

// ---------------------------------------------------------------- merged weight prep
// block ranges: [0,128) w2perm | [128,256) wb1 | [256,1280) wb2 | [1280,4405) xcvt
//               4405 wa1 | [4406,4410) wa2 | [4410,4412) w1t
// wa*/wd* prescaled by LOG2E so agg kernels can use raw v_exp_f32 (leaky is pos-homogeneous).
__global__ __launch_bounds__(256) void k_prep(const float* __restrict__ w2,
                                              const float* __restrict__ W1,
                                              const float* __restrict__ W2,
                                              const float* __restrict__ a1s,
                                              const float* __restrict__ a1d,
                                              const float* __restrict__ a2s,
                                              const float* __restrict__ a2d,
                                              const float* __restrict__ x,
                                              const float* __restrict__ b2,
                                              const float* __restrict__ w1,
                                              __half* __restrict__ wtt,
                                              __half* __restrict__ wb1,
                                              __half* __restrict__ wb2,
                                              float* __restrict__ wa1,
                                              float* __restrict__ wd1,
                                              float* __restrict__ wa2,
                                              float* __restrict__ wd2,
                                              __half* __restrict__ xf,
                                              float* __restrict__ xb,
                                              __half* __restrict__ w1t) {
    int bid = blockIdx.x, t = threadIdx.x;
    if (bid < 128) {                             // enc_w2 perm: wtt[co][i]
        int idx = bid * 256 + t;                 // co*32+i
        int co = idx >> 5, i = idx & 31;
        wtt[idx] = __float2half(w2[(co >> 5) * 1024 + i * 32 + (co & 31)]);
    } else if (bid < 256) {                      // wb1[d][k], k=h*32+i
        int idx = (bid - 128) * 256 + t;
        int d = idx >> 7, k = idx & 127;
        int h = k >> 5, i = k & 31;
        wb1[idx] = __float2half(0.25f * W1[i * 1024 + h * 256 + d]);
    } else if (bid < 1280) {                     // wb2[d][k], k=h*256+i
        int idx = (bid - 256) * 256 + t;
        int d = idx >> 10, k = idx & 1023;
        int h = k >> 8, i = k & 255;
        wb2[idx] = __float2half(0.25f * W2[i * 1024 + h * 256 + d]);
    } else if (bid < 4405) {                     // xcvt
        int idx = (bid - 1280) * 256 + t;
        if (idx >= N_NODES * 32) return;
        int n = idx >> 5, o = idx & 31;
        xf[idx] = __float2half(x[idx]);
        float s = 0.f;
        for (int i = 0; i < 32; ++i) s += x[n * 32 + i] * b2[i * 32 + o];
        xb[idx] = s;
    } else if (bid == 4405) {                    // wa1/wd1 (128 lanes), log2e-prescaled
        if (t >= 128) return;
        int h = t >> 5, i = t & 31;
        float s = 0.f, sd = 0.f;
        for (int d = 0; d < 256; ++d) {
            float w = W1[i * 1024 + h * 256 + d];
            s  += w * a1s[h * 256 + d];
            sd += w * a1d[h * 256 + d];
        }
        wa1[t] = s * LOG2E; wd1[t] = sd * LOG2E;
    } else if (bid < 4410) {                     // wa2/wd2, log2e-prescaled
        int idx = (bid - 4406) * 256 + t;        // h*256+i
        if (idx >= 1024) return;
        int h = idx >> 8, i = idx & 255;
        float s = 0.f, sd = 0.f;
        for (int d = 0; d < 256; ++d) {
            float w = W2[i * 1024 + h * 256 + d];
            s  += w * a2s[h * 256 + d];
            sd += w * a2d[h * 256 + d];
        }
        wa2[idx] = s * LOG2E; wd2[idx] = sd * LOG2E;
    } else {                                     // w1t[j][k] = fp16(w1[k*32+j])
        int idx = (bid - 4410) * 256 + t;        // j*16+k
        if (idx >= 32 * EDFD) return;
        int j = idx >> 4, k = idx & 15;
        w1t[idx] = __float2half(w1[k * 32 + j]);
    }
}

// ---------------------------------------------------------------- NNConv via MFMA
// wave per src: msgE[16 edges,32] = relu(eaP[16,16] @ w1 + b1) @ T[src] + xb[src]
__global__ __launch_bounds__(256) void k_msg3(const int* __restrict__ rowptr2,
                                              const int* __restrict__ posMap,
                                              const __half* __restrict__ eaP,
                                              const __half* __restrict__ w1t,
                                              const float* __restrict__ b1,
                                              const __half* __restrict__ T,
                                              const float* __restrict__ xb,
                                              __half* __restrict__ msgE) {
    int wv = threadIdx.x >> 6, lane = threadIdx.x & 63;
    int src = blockIdx.x * 4 + wv;
    if (src >= N_NODES) return;
    int r0 = rowptr2[src], r1 = rowptr2[src + 1];
    if (r0 == r1) return;
    int lr = lane & 15, lk = (lane >> 4) * 8;

    // B fragments from T[src] (layout [j*32+o]): col lr (B0) and 16+lr (B1), k = lk..lk+7
    half8v bf0, bf1;
    const __half* Tp = T + (size_t)src * 1024;
    #pragma unroll
    for (int q = 0; q < 8; ++q) {
        bf0[q] = (_Float16)__half2float(Tp[(lk + q) * 32 + lr]);
        bf1[q] = (_Float16)__half2float(Tp[(lk + q) * 32 + 16 + lr]);
    }

    // w1 rows lk..lk+7 (fp16, 16 k each) held in registers
    __half2 w1r[8][EDFD / 2];
    #pragma unroll
    for (int q = 0; q < 8; ++q) {
        const __half2* wp = (const __half2*)(w1t + (lk + q) * EDFD);
        #pragma unroll
        for (int k2 = 0; k2 < EDFD / 2; ++k2) w1r[q][k2] = wp[k2];
    }
    float b1r[8];
    #pragma unroll
    for (int q = 0; q < 8; ++q) b1r[q] = b1[lk + q];

    float xb0 = xb[src * 32 + lr], xb1 = xb[src * 32 + 16 + lr];
    int rbase = (lane >> 4) * 4;

    for (int t0 = r0; t0 < r1; t0 += 16) {
        int e = t0 + lr;
        bool ok = (e < r1);
        // MLP for edge e, outputs j = lk..lk+7
        half8v afr;
        if (ok) {
            const __half2* ep = (const __half2*)(eaP + (size_t)e * EDFD);
            __half2 ea2[EDFD / 2];
            #pragma unroll
            for (int k2 = 0; k2 < EDFD / 2; ++k2) ea2[k2] = ep[k2];
            #pragma unroll
            for (int q = 0; q < 8; ++q) {
                float s = b1r[q];
                #pragma unroll
                for (int k2 = 0; k2 < EDFD / 2; ++k2) {
                    float2 v = __half22float2(ea2[k2]);
                    float2 w = __half22float2(w1r[q][k2]);
                    s += v.x * w.x + v.y * w.y;
                }
                afr[q] = (_Float16)fmaxf(s, 0.f);
            }
        } else {
            #pragma unroll
            for (int q = 0; q < 8; ++q) afr[q] = (_Float16)0.f;
        }
        f32x4 c0 = {0.f, 0.f, 0.f, 0.f}, c1 = {0.f, 0.f, 0.f, 0.f};
        c0 = __builtin_amdgcn_mfma_f32_16x16x32_f16(afr, bf0, c0, 0, 0, 0);
        c1 = __builtin_amdgcn_mfma_f32_16x16x32_f16(afr, bf1, c1, 0, 0, 0);
        #pragma unroll
        for (int r = 0; r < 4; ++r) {
            int er = t0 + rbase + r;
            if (er < r1) {
                int pm = posMap[er];
                msgE[(size_t)pm * 32 + lr]      = __float2half(c0[r] + xb0);
                msgE[(size_t)pm * 32 + 16 + lr] = __float2half(c1[r] + xb1);
            }
        }
    }
}

// h0 = relu(sum(msgE)/deg + x@root_w + bias) -> fp16, fused layer1 es/ed (log2-space)
__global__ __launch_bounds__(256) void k_h0e(const float* __restrict__ x,
                                             const float* __restrict__ root_w,
                                             const float* __restrict__ nn_bias,
                                             const __half* __restrict__ msgE,
                                             const int* __restrict__ rowptr,
                                             const float* __restrict__ wa,
                                             const float* __restrict__ wd,
                                             __half* __restrict__ h0f,
                                             float* __restrict__ es,
                                             float* __restrict__ ed) {
    int t = threadIdx.x;
    int ng = t >> 5, o = t & 31;
    int n = blockIdx.x * 8 + ng;
    if (n >= N_NODES) return;
    float s = nn_bias[o];
    for (int k = 0; k < IN_DIM; ++k) s += x[n * IN_DIM + k] * root_w[k * 32 + o];
    int r0 = rowptr[n], r1 = rowptr[n + 1];
    float aggv = 0.f;
    for (int r = r0; r < r1; ++r)
        aggv += __half2float(msgE[(size_t)r * 32 + o]);  // sequential 64B reads per group
    float c = fmaxf((float)(r1 - r0), 1.f);
    s += aggv / c;
    float v = fmaxf(s, 0.f);
    h0f[n * IN_DIM + o] = __float2half(v);
    #pragma unroll
    for (int h = 0; h < 4; ++h) {
        float ss = v * wa[h * 32 + o];
        float dd = v * wd[h * 32 + o];
        #pragma unroll
        for (int off = 16; off; off >>= 1) {
            ss += __shfl_down(ss, off, 32);
            dd += __shfl_down(dd, off, 32);
        }
        if (o == 0) { es[n * 4 + h] = ss; ed[n * 4 + h] = dd; }
    }
}

// ---------------------------------------------------------------- GEMM 1: T = xf @ wtt^T, out [M,1024] fp16
__global__ __launch_bounds__(256, 2) void k_gemT(const __half* __restrict__ A,
                                                 const __half* __restrict__ Wt,
                                                 __half* __restrict__ C) {
    __shared__ __half cst[4][16 * 36];
    int t = threadIdx.x, wid = t >> 6, lane = t & 63;
    int lr = lane & 15, lk = (lane >> 4) * 8;

    int bid = blockIdx.x;
    int xcd = bid & 7, j = bid >> 3;
    int sx = j & 31;
    int y = ((j >> 5) << 3) | xcd;            // 0..103
    int n0 = sx * 32;

    half8v bfr[2];
    #pragma unroll
    for (int c = 0; c < 2; ++c)
        bfr[c] = *(const half8v*)(Wt + (size_t)(n0 + c * 16 + lr) * 32 + lk);

    int tb = (y * 4 + wid) * 4;
    for (int pp = 0; pp < 4; pp += 2) {
        int tA = tb + pp;
        if (tA >= N_TILES) break;
        int mA = tA * 16, mB = mA + 16;
        half8v aA = *(const half8v*)(A + (size_t)(mA + lr) * 32 + lk);
        half8v aB = *(const half8v*)(A + (size_t)(mB + lr) * 32 + lk);
        f32x4 acc[2][2];
        #pragma unroll
        for (int i = 0; i < 2; ++i)
            #pragma unroll
            for (int c = 0; c < 2; ++c)
                acc[i][c] = (f32x4){0.f, 0.f, 0.f, 0.f};
        acc[0][0] = __builtin_amdgcn_mfma_f32_16x16x32_f16(aA, bfr[0], acc[0][0], 0, 0, 0);
        acc[0][1] = __builtin_amdgcn_mfma_f32_16x16x32_f16(aA, bfr[1], acc[0][1], 0, 0, 0);
        acc[1][0] = __builtin_amdgcn_mfma_f32_16x16x32_f16(aB, bfr[0], acc[1][0], 0, 0, 0);
        acc[1][1] = __builtin_amdgcn_mfma_f32_16x16x32_f16(aB, bfr[1], acc[1][1], 0, 0, 0);

        int rbase = (lane >> 4) * 4;
        #pragma unroll
        for (int ti = 0; ti < 2; ++ti) {
            #pragma unroll
            for (int c = 0; c < 2; ++c)
                #pragma unroll
                for (int r = 0; r < 4; ++r)
                    cst[wid][(rbase + r) * 36 + c * 16 + lr] = __float2half(acc[ti][c][r]);
            int m0 = ti ? mB : mA;
            #pragma unroll
            for (int p = 0; p < 2; ++p) {
                int row = p * 8 + (lane >> 3), hb = lane & 7;
                float2 v = *(const float2*)((const char*)&cst[wid][0] + row * 72 + hb * 8);
                *(float2*)((char*)C + ((size_t)(m0 + row) * 1024 + n0) * 2 + hb * 8) = v;
            }
        }
    }
}

// ---------------------------------------------------------------- GEMM 2: head-mean-folded, out [M,256]
// block = 8 row-tiles x 64 cols; wave owns 2 tiles; A-loads hoisted; A re-read 4x.
// Staging via global_load_lds (linear LDS dest, pre-swizzled global src; same byte placement).
// FUSE_ED: accumulate layer-2 attention scalars es/ed from epilogue values (atomic partials).
template <int K, typename OT, bool FUSE_ED>
__global__ __launch_bounds__(256, 3) void k_gemmo(const __half* __restrict__ A,
                                                  const __half* __restrict__ Wt,
                                                  const float* __restrict__ bias,
                                                  OT* __restrict__ C,
                                                  const float* __restrict__ wa,
                                                  const float* __restrict__ wd,
                                                  float* __restrict__ es,
                                                  float* __restrict__ ed) {
    constexpr int CK  = 128;                    // LDS chunk K-extent
    constexpr int KC  = K / CK;
    constexpr int KSC = CK / 32;
    constexpr int CB  = CK * 2;                 // bytes per LDS col (256)
    __shared__ __half bs[2][64 * CK];           // 64 cols x CK (16KB per buffer)
    __shared__ float cst[4][16 * 36];
    int t = threadIdx.x, wid = t >> 6, lane = t & 63;
    int lr = lane & 15, lk = (lane >> 4) * 8;

    int bid = blockIdx.x;
    int xcd = bid & 7, rest = bid >> 3;
    int strip = rest & 3, yhi = rest >> 2;
    int y = yhi * 8 + xcd;                      // row-group (8 tiles); same y -> same XCD
    if (y >= 196) return;                       // block-uniform early exit (196*8=1568>=1564)
    int n0 = strip * 64;
    float bv[4];
    #pragma unroll
    for (int c = 0; c < 4; ++c) bv[c] = bias[n0 + c * 16 + lr];
    int tb = y * 8 + wid * 2;                   // wave's first tile
    int tA0 = tb     < N_TILES ? tb     : N_TILES - 1;   // clamped (no barrier divergence)
    int tA1 = tb + 1 < N_TILES ? tb + 1 : N_TILES - 1;
    const int swz = (lr & 7) << 4;

    f32x4 acc[2][4];                            // [tile][colblock]
    #pragma unroll
    for (int i = 0; i < 2; ++i)
        #pragma unroll
        for (int c = 0; c < 4; ++c)
            acc[i][c] = (f32x4){0.f, 0.f, 0.f, 0.f};

    // async stage: LDS[lo] = Wt[g(lo ^ swz(col))] -- identical placement to reg-staged XOR write
    #define STAGE_CHUNK(BUF, KCN)                                                              \
        _Pragma("unroll")                                                                      \
        for (int it = 0; it < (64 * CB) / (256 * 16); ++it) {                                  \
            int lo = it * 4096 + wid * 1024 + lane * 16;                                       \
            int col = lo >> 8;                                                                 \
            int go = lo ^ ((col & 7) << 4);                                                    \
            const char* sp_ = (const char*)Wt + ((size_t)(n0 + col) * K + (KCN) * CK) * 2      \
                              + (go & (CB - 1));                                               \
            __builtin_amdgcn_global_load_lds(                                                  \
                (const __attribute__((address_space(1))) void*)sp_,                            \
                (__attribute__((address_space(3))) void*)((char*)bs[BUF] + it * 4096 + wid * 1024), \
                16, 0, 0);                                                                     \
        }

    STAGE_CHUNK(0, 0)
    __syncthreads();

    const __half* pA0 = A + (size_t)(tA0 * 16 + lr) * K + lk;
    const __half* pA1 = A + (size_t)(tA1 * 16 + lr) * K + lk;

    for (int kc = 0; kc < KC; ++kc) {
        int cur = kc & 1;
        if (kc + 1 < KC) {
            STAGE_CHUNK(cur ^ 1, kc + 1)
        }
        // hoist all A fragments for this chunk (8 outstanding 16B loads)
        half8v aH0[KSC], aH1[KSC];
        #pragma unroll
        for (int ks = 0; ks < KSC; ++ks) {
            aH0[ks] = *(const half8v*)(pA0 + kc * CK + ks * 32);
            aH1[ks] = *(const half8v*)(pA1 + kc * CK + ks * 32);
        }
        #pragma unroll
        for (int ks = 0; ks < KSC; ++ks) {
            #pragma unroll
            for (int c = 0; c < 4; ++c) {
                half8v b = *(const half8v*)((const char*)bs[cur] +
                            (((c * 16 + lr) * CB + lk * 2 + ks * 64) ^ swz));
                acc[0][c] = __builtin_amdgcn_mfma_f32_16x16x32_f16(aH0[ks], b, acc[0][c], 0, 0, 0);
                acc[1][c] = __builtin_amdgcn_mfma_f32_16x16x32_f16(aH1[ks], b, acc[1][c], 0, 0, 0);
            }
        }
        if (kc + 1 < KC) __syncthreads();
    }
    #undef STAGE_CHUNK

    int rbase = (lane >> 4) * 4;
    #pragma unroll
    for (int ti = 0; ti < 2; ++ti) {
        if (tb + ti >= N_TILES) break;
        int m0 = (tb + ti) * 16;
        int row = lane >> 2, cg = lane & 3;     // 16 rows x 4 col-groups of 8
        #pragma unroll
        for (int half = 0; half < 2; ++half) {
            #pragma unroll
            for (int c = 0; c < 2; ++c)
                #pragma unroll
                for (int r = 0; r < 4; ++r)
                    cst[wid][(rbase + r) * 36 + c * 16 + lr] =
                        fmaxf(acc[ti][half * 2 + c][r] + bv[half * 2 + c], 0.f);
            int colb = n0 + half * 32;
            const float* sp = &cst[wid][row * 36 + cg * 8];
            if constexpr (sizeof(OT) == 2) {
                __half2 o0 = __float22half2_rn(make_float2(sp[0], sp[1]));
                __half2 o1 = __float22half2_rn(make_float2(sp[2], sp[3]));
                __half2 o2 = __float22half2_rn(make_float2(sp[4], sp[5]));
                __half2 o3 = __float22half2_rn(make_float2(sp[6], sp[7]));
                float4 v = make_float4(__uint_as_float(*(unsigned*)&o0), __uint_as_float(*(unsigned*)&o1),
                                       __uint_as_float(*(unsigned*)&o2), __uint_as_float(*(unsigned*)&o3));
                *(float4*)((__half*)C + (size_t)(m0 + row) * 256 + colb + cg * 8) = v;
            } else {
                float4 v0 = make_float4(sp[0], sp[1], sp[2], sp[3]);
                float4 v1 = make_float4(sp[4], sp[5], sp[6], sp[7]);
                float* cp = (float*)C + (size_t)(m0 + row) * 256 + colb + cg * 8;
                *(float4*)cp = v0;
                *(float4*)(cp + 4) = v1;
            }
            if constexpr (FUSE_ED) {
                int rowg = m0 + row;
                #pragma unroll
                for (int h = 0; h < 4; ++h) {
                    float pes = 0.f, ped = 0.f;
                    #pragma unroll
                    for (int d = 0; d < 8; ++d) {
                        float vv = sp[d];
                        pes += vv * wa[h * 256 + colb + cg * 8 + d];
                        ped += vv * wd[h * 256 + colb + cg * 8 + d];
                    }
                    // reduce across the 4 cg lanes (consecutive lanes 4*row..4*row+3)
                    pes += __shfl_down(pes, 1, 4); pes += __shfl_down(pes, 2, 4);
                    ped += __shfl_down(ped, 1, 4); ped += __shfl_down(ped, 2, 4);
                    if (cg == 0 && rowg < N_NODES) {
                        atomicAdd(&es[rowg * 4 + h], pes);
                        atomicAdd(&ed[rowg * 4 + h], ped);
                    }
                }
            }
        }
    }
}

// ---------------------------------------------------------------- aggregation (softmax fused; raw v_exp_f32)
__global__ __launch_bounds__(256) void k_agg1(const int* __restrict__ rowptr,
                                              const int* __restrict__ csrc,
                                              const float* __restrict__ es,
                                              const float* __restrict__ ed,
                                              const __half* __restrict__ h0f,
                                              __half* __restrict__ agg0) {
    int dst = blockIdx.x * 4 + (threadIdx.x >> 6);
    if (dst >= N_NODES) return;
    int lane = threadIdx.x & 63;
    int h = lane >> 4, i2 = lane & 15;
    float edv = ed[dst * 4 + h];
    float vself = leaky(es[dst * 4 + h] + edv);   // shift = self-loop score (w_self = 1)
    float dn = 1.f;
    int r0 = rowptr[dst], r1 = rowptr[dst + 1];

    __half2 hv = *(const __half2*)(h0f + (size_t)dst * 32 + i2 * 2);
    float2 f = __half22float2(hv);
    float ax = f.x, ay = f.y;
    for (int r = r0; r < r1; ++r) {
        int src = csrc[r];
        float w = fexp2(leaky(es[src * 4 + h] + edv) - vself);
        dn += w;
        __half2 sv = *(const __half2*)(h0f + (size_t)src * 32 + i2 * 2);
        float2 g = __half22float2(sv);
        ax += w * g.x; ay += w * g.y;
    }
    float inv = 1.f / (dn + 1e-16f);
    *(__half2*)(agg0 + (size_t)dst * 128 + h * 32 + i2 * 2) =
        __float22half2_rn(make_float2(ax * inv, ay * inv));
}

// 2 dsts per wave (32-lane groups); each lane covers 8 dims; 2 independent gather streams.
__global__ __launch_bounds__(256) void k_agg2(const int* __restrict__ rowptr,
                                              const int* __restrict__ csrc,
                                              const float* __restrict__ es,
                                              const float* __restrict__ ed,
                                              const __half* __restrict__ h1f,
                                              __half* __restrict__ agg1) {
    int wv = threadIdx.x >> 6, lane = threadIdx.x & 63;
    int g = lane >> 5, l = lane & 31;
    int dst = blockIdx.x * 8 + wv * 2 + g;
    if (dst >= N_NODES) return;
    float vs[4], edv[4], dn[4];
    float acc[4][8];
    {
        float4 q = *(const float4*)(h1f + (size_t)dst * 256 + l * 8);
        const __half2* hq = (const __half2*)&q;
        float2 f0 = __half22float2(hq[0]), f1 = __half22float2(hq[1]);
        float2 f2 = __half22float2(hq[2]), f3 = __half22float2(hq[3]);
        #pragma unroll
        for (int h = 0; h < 4; ++h) {
            edv[h] = ed[dst * 4 + h];
            vs[h] = leaky(es[dst * 4 + h] + edv[h]);
            dn[h] = 1.f;                          // w_self = 1 under self-loop shift
            acc[h][0] = f0.x; acc[h][1] = f0.y; acc[h][2] = f1.x; acc[h][3] = f1.y;
            acc[h][4] = f2.x; acc[h][5] = f2.y; acc[h][6] = f3.x; acc[h][7] = f3.y;
        }
    }
    int r0 = rowptr[dst], r1 = rowptr[dst + 1];
    for (int r = r0; r < r1; ++r) {
        int src = csrc[r];
        float4 esv = *(const float4*)(es + (size_t)src * 4);
        float w0 = fexp2(leaky(esv.x + edv[0]) - vs[0]);
        float w1 = fexp2(leaky(esv.y + edv[1]) - vs[1]);
        float w2 = fexp2(leaky(esv.z + edv[2]) - vs[2]);
        float w3 = fexp2(leaky(esv.w + edv[3]) - vs[3]);
        dn[0] += w0; dn[1] += w1; dn[2] += w2; dn[3] += w3;
        float4 q = *(const float4*)(h1f + (size_t)src * 256 + l * 8);
        const __half2* hq = (const __half2*)&q;
        float2 f0 = __half22float2(hq[0]), f1 = __half22float2(hq[1]);
        float2 f2 = __half22float2(hq[2]), f3 = __half22float2(hq[3]);
        acc[0][0] += w0 * f0.x; acc[0][1] += w0 * f0.y; acc[0][2] += w0 * f1.x; acc[0][3] += w0 * f1.y;
        acc[0][4] += w0 * f2.x; acc[0][5] += w0 * f2.y; acc[0][6] += w0 * f3.x; acc[0][7] += w0 * f3.y;
        acc[1][0] += w1 * f0.x; acc[1][1] += w1 * f0.y; acc[1][2] += w1 * f1.x; acc[1][3] += w1 * f1.y;
        acc[1][4] += w1 * f2.x; acc[1][5] += w1 * f2.y; acc[1][6] += w1 * f3.x; acc[1][7] += w1 * f3.y;
        acc[2][0] += w2 * f0.x; acc[2][1] += w2 * f0.y; acc[2][2] += w2 * f1.x; acc[2][3] += w2 * f1.y;
        acc[2][4] += w2 * f2.x; acc[2][5] += w2 * f2.y; acc[2][6] += w2 * f3.x; acc[2][7] += w2 * f3.y;
        acc[3][0] += w3 * f0.x; acc[3][1] += w3 * f0.y; acc[3][2] += w3 * f1.x; acc[3][3] += w3 * f1.y;
        acc[3][4] += w3 * f2.x; acc[3][5] += w3 * f2.y; acc[3][6] += w3 * f3.x; acc[3][7] += w3 * f3.y;
    }
    #pragma unroll
    for (int h = 0; h < 4; ++h) {
        float inv = 1.f / (dn[h] + 1e-16f);
        __half2 o0 = __float22half2_rn(make_float2(acc[h][0] * inv, acc[h][1] * inv));
        __half2 o1 = __float22half2_rn(make_float2(acc[h][2] * inv, acc[h][3] * inv));
        __half2 o2 = __float22half2_rn(make_float2(acc[h][4] * inv, acc[h][5] * inv));
        __half2 o3 = __float22half2_rn(make_float2(acc[h][6] * inv, acc[h][7] * inv));
        float4 v = make_float4(__uint_as_float(*(unsigned*)&o0), __uint_as_float(*(unsigned*)&o1),
                               __uint_as_float(*(unsigned*)&o2), __uint_as_float(*(unsigned*)&o3));
        *(float4*)(agg1 + (size_t)dst * 1024 + h * 256 + l * 8) = v;
    }
}

// ---------------------------------------------------------------- heads (wire + pool merged)
__global__ __launch_bounds__(256) void k_wirepool(const int* __restrict__ wm,
                                                  const float* __restrict__ h2,
                                                  const float* __restrict__ ww,
                                                  const float* __restrict__ wb,
                                                  const int* __restrict__ batch,
                                                  float* __restrict__ out,
                                                  float* __restrict__ pooled,
                                                  float* __restrict__ gcnt) {
    int bid = blockIdx.x;
    if (bid < KWIRE / 4) {                       // wire head
        int k = bid * 4 + (threadIdx.x >> 6);
        int lane = threadIdx.x & 63;
        int n = wm[k];
        float s = 0.f;
        for (int d = lane; d < 256; d += 64) s += h2[(size_t)n * 256 + d] * ww[d];
        #pragma unroll
        for (int off = 32; off; off >>= 1) s += __shfl_down(s, off);
        if (lane == 0) out[k] = s + wb[0];
        return;
    }
    // segmented pooling
    int n0 = (bid - KWIRE / 4) * POOL_NB;
    int n1 = n0 + POOL_NB; if (n1 > N_NODES) n1 = N_NODES;
    int d = threadIdx.x;
    int cur = batch[n0];
    float acc = 0.f, cnt = 0.f;
    for (int n = n0; n < n1; ++n) {
        int g = batch[n];
        if (g != cur) {
            atomicAdd(&pooled[cur * 256 + d], acc);
            if (d == 0) atomicAdd(&gcnt[cur], cnt);
            acc = 0.f; cnt = 0.f; cur = g;
        }
        acc += h2[(size_t)n * 256 + d];
        cnt += 1.f;
    }
    atomicAdd(&pooled[cur * 256 + d], acc);
    if (d == 0) atomicAdd(&gcnt[cur], cnt);
}

__global__ __launch_bounds__(256) void k_act(const float* __restrict__ pooled,
                                             const float* __restrict__ gcnt,
                                             const float* __restrict__ aw,
                                             const float* __restrict__ ab,
                                             float* __restrict__ out) {
    int u = blockIdx.x * 4 + (threadIdx.x >> 6);
    int lane = threadIdx.x & 63;
    if (u >= NGRAPH * NACT) return;
    int g = u >> 4, a = u & 15;
    float c = fmaxf(gcnt[g], 1.f);
    float s = 0.f;
    for (int d = lane; d < 256; d += 64) s += pooled[g * 256 + d] * aw[d * 16 + a];
    #pragma unroll
    for (int off = 32; off; off >>= 1) s += __shfl_down(s, off);
    if (lane == 0) out[KWIRE + u] = s / c + ab[a];
}

// ---------------------------------------------------------------- launch
extern "C" void kernel_launch(void* const* d_in, const int* in_sizes, int n_in,
                              void* d_out, int out_size, void* d_ws, size_t ws_size,
                              hipStream_t stream) {
    const float* x        = (const float*)d_in[0];
    const float* edge_attr= (const float*)d_in[1];
    const int*   wire_mask= (const int*)d_in[2];
    const int*   edge_idx = (const int*)d_in[3];
    const int*   batch    = (const int*)d_in[4];
    const float* enc_w1   = (const float*)d_in[5];
    const float* enc_b1   = (const float*)d_in[6];
    const float* enc_w2   = (const float*)d_in[7];
    const float* enc_b2   = (const float*)d_in[8];
    const float* root_w   = (const float*)d_in[9];
    const float* nn_bias  = (const float*)d_in[10];
    const float* gat1_w   = (const float*)d_in[11];
    const float* gat1_asrc= (const float*)d_in[12];
    const float* gat1_adst= (const float*)d_in[13];
    const float* gat1_b   = (const float*)d_in[14];
    const float* gat2_w   = (const float*)d_in[15];
    const float* gat2_asrc= (const float*)d_in[16];
    const float* gat2_adst= (const float*)d_in[17];
    const float* gat2_b   = (const float*)d_in[18];
    const float* wire_w   = (const float*)d_in[19];
    const float* wire_b   = (const float*)d_in[20];
    const float* act_w    = (const float*)d_in[21];
    const float* act_b    = (const float*)d_in[22];
    float* out = (float*)d_out;

    float* ws = (float*)d_ws;
    size_t off = 0;
    __half* T16   = (__half*)(ws + off); off += (size_t)M_PAD * 1024 / 2;
    __half* agg1f = (__half*)(ws + off); off += (size_t)M_PAD * 1024 / 2;
    __half* agg0f = (__half*)(ws + off); off += (size_t)M_PAD * 128 / 2;
    __half* h0f   = (__half*)(ws + off); off += (size_t)M_PAD * 32 / 2;
    __half* h1f   = (__half*)(ws + off); off += (size_t)M_PAD * 256 / 2;
    __half* xf    = (__half*)(ws + off); off += (size_t)M_PAD * 32 / 2;
    __half* eaP   = (__half*)(ws + off); off += (size_t)N_EDGES * EDFD / 2;
    __half* msgE  = (__half*)(ws + off); off += (size_t)N_EDGES * 32 / 2;
    float* xb     = ws + off; off += 800000;
    float* esb    = ws + off; off += 100000;
    float* edb    = ws + off; off += 100000;
    float* h2     = ws + off; off += (size_t)M_PAD * 256;
    float* pooled = ws + off; off += NGRAPH * 256;
    float* gcnt   = ws + off; off += NGRAPH;
    int* deg      = (int*)(ws + off); off += 25600;   // zero-region start
    int* deg2     = (int*)(ws + off); off += 25600;
    int* cursor   = (int*)(ws + off); off += 25600;
    int* cursor2  = (int*)(ws + off); off += 25600;   // zero-region end
    int* rowptr   = (int*)(ws + off); off += 25600;
    int* rowptr2  = (int*)(ws + off); off += 25600;
    int* csrc     = (int*)(ws + off); off += N_EDGES;
    int* cdst     = (int*)(ws + off); off += N_EDGES;
    int* posMap   = (int*)(ws + off); off += N_EDGES;
    __half* wtt   = (__half*)(ws + off); off += 16384;    // enc_w2 perm [1024][32]
    __half* wb1t  = (__half*)(ws + off); off += 16384;    // [256][128]
    __half* wb2t  = (__half*)(ws + off); off += 131072;   // [256][1024]
    __half* w1t   = (__half*)(ws + off); off += 256;      // [32 j][16 k]
    float* wa1    = ws + off; off += 128;
    float* wd1    = ws + off; off += 128;
    float* wa2    = ws + off; off += 1024;
    float* wd2    = ws + off; off += 1024;
    float* esb2   = ws + off; off += 100000;   // layer-2 es (atomic-accumulated)
    float* edb2   = ws + off; off += 100000;   // layer-2 ed

    const int GBT = 3328;   // T-gemm: 8 xcd x 13 ygroups x 32 strips
    const int GBO = 800;    // out-256 gemms: 8 xcd x 4 strips x 25 yhi (y>=196 early-exit)

    // ---- CSR build ----
    hipMemsetAsync(deg, 0, 4 * 25600 * sizeof(int), stream);
    hipMemsetAsync(esb2, 0, 2 * 100000 * sizeof(float), stream);
    k_deg2<<<(N_EDGES + 255) / 256, 256, 0, stream>>>(edge_idx, deg, deg2);
    k_scan2<<<2, 1024, 0, stream>>>(deg, rowptr, deg2, rowptr2);
    k_scatter2<<<(N_EDGES + 255) / 256, 256, 0, stream>>>(edge_idx, edge_attr, rowptr, rowptr2,
                                                          cursor, cursor2, csrc, cdst, posMap, eaP);

    // ---- merged weight prep ----
    k_prep<<<4412, 256, 0, stream>>>(enc_w2, gat1_w, gat2_w, gat1_asrc, gat1_adst,
                                     gat2_asrc, gat2_adst, x, enc_b2, enc_w1,
                                     wtt, wb1t, wb2t, wa1, wd1, wa2, wd2, xf, xb, w1t);

    // ---- NNConv ----
    k_gemT<<<GBT, 256, 0, stream>>>(xf, wtt, T16);
    k_msg3<<<(N_NODES + 3) / 4, 256, 0, stream>>>(rowptr2, posMap, eaP,
                                                  w1t, enc_b1, T16, xb, msgE);
    k_h0e<<<(N_NODES + 7) / 8, 256, 0, stream>>>(x, root_w, nn_bias, msgE, rowptr,
                                                 wa1, wd1, h0f, esb, edb);

    // ---- GAT layer 1 (es/ed for layer 2 fused into GEMM epilogue) ----
    k_agg1<<<(N_NODES + 3) / 4, 256, 0, stream>>>(rowptr, csrc, esb, edb, h0f, agg0f);
    k_gemmo<128, __half, true><<<GBO, 256, 0, stream>>>(agg0f, wb1t, gat1_b, h1f,
                                                        wa2, wd2, esb2, edb2);

    // ---- GAT layer 2 ----
    k_agg2<<<(N_NODES + 7) / 8, 256, 0, stream>>>(rowptr, csrc, esb2, edb2, h1f, agg1f);
    k_gemmo<1024, float, false><<<GBO, 256, 0, stream>>>(agg1f, wb2t, gat2_b, h2,
                                                         nullptr, nullptr, nullptr, nullptr);

    // ---- heads ----
    hipMemsetAsync(pooled, 0, (NGRAPH * 256 + NGRAPH) * sizeof(float), stream);
    k_wirepool<<<KWIRE / 4 + (N_NODES + POOL_NB - 1) / POOL_NB, 256, 0, stream>>>(
        wire_mask, h2, wire_w, wire_b, batch, out, pooled, gcnt);
    k_act<<<NGRAPH * NACT / 4, 256, 0, stream>>>(pooled, gcnt, act_w, act_b, out);
}